// Round 1
// baseline (178.572 us; speedup 1.0000x reference)
//
#include <hip/hip_runtime.h>

#define C 128
#define NPIX 16384      // 4 * 64 * 64
#define THREE_C 384

// ---------------- Kernel 1: qkv = x @ W_qkv (M=16384, N=384, K=128) ----------------
// 16 rows per block, 384 threads (one output column each), x rows staged in LDS.
__global__ __launch_bounds__(384) void qkv_kernel(const float* __restrict__ x,
                                                  const float* __restrict__ Wqkv,
                                                  float* __restrict__ q,
                                                  float* __restrict__ k,
                                                  float* __restrict__ v) {
    __shared__ float xs[16 * C];
    const int p0 = blockIdx.x * 16;
    const int tid = threadIdx.x;
    for (int e = tid; e < 16 * C; e += 384) xs[e] = x[p0 * C + e];
    __syncthreads();

    float acc[16];
#pragma unroll
    for (int r = 0; r < 16; ++r) acc[r] = 0.f;

    const int n = tid;  // 0..383 output column
    for (int c = 0; c < C; ++c) {
        const float w = Wqkv[c * THREE_C + n];
#pragma unroll
        for (int r = 0; r < 16; ++r) acc[r] += xs[r * C + c] * w;
    }

    float* dst;
    int col;
    if (n < C)          { dst = q; col = n; }
    else if (n < 2 * C) { dst = k; col = n - C; }
    else                { dst = v; col = n - 2 * C; }
#pragma unroll
    for (int r = 0; r < 16; ++r) dst[(p0 + r) * C + col] = acc[r];
}

// ---------------- Kernel 2: local attention, one wave (64 lanes) per pixel ----------------
__global__ __launch_bounds__(256) void attn_kernel(const float* __restrict__ x,
                                                   const float* __restrict__ Wwidth,
                                                   const float* __restrict__ bwidth,
                                                   const float* __restrict__ q,
                                                   const float* __restrict__ k,
                                                   const float* __restrict__ v,
                                                   float* __restrict__ y) {
    const int wave = threadIdx.x >> 6;
    const int lane = threadIdx.x & 63;
    const int p = blockIdx.x * 4 + wave;      // pixel index
    const int ij = p & 4095;
    const int i = ij >> 6;
    const int j = ij & 63;

    // width = sigmoid(x_row . W_width + b) * sqrt(18) + 0.5  (in-wave dot + butterfly)
    float wpart = x[p * C + lane] * Wwidth[lane] + x[p * C + 64 + lane] * Wwidth[64 + lane];
#pragma unroll
    for (int off = 32; off; off >>= 1) wpart += __shfl_xor(wpart, off);
    const float z = wpart + bwidth[0];
    const float wd = (1.f / (1.f + __expf(-z))) * 4.242640687f + 0.5f;

    const float q0 = q[p * C + lane];
    const float q1 = q[p * C + 64 + lane];

    float score[49];
#pragma unroll
    for (int w = 0; w < 49; ++w) {
        const int di = w / 7 - 3, dj = w % 7 - 3;
        const int ii = i + di, jj = j + dj;
        const bool inb = ((unsigned)ii < 64u) && ((unsigned)jj < 64u);
        const int np = p + di * 64 + dj;
        float part = 0.f;
        if (inb) {
            part = q0 * k[np * C + lane] + q1 * k[np * C + 64 + lane];
        }
#pragma unroll
        for (int off = 32; off; off >>= 1) part += __shfl_xor(part, off);
        // OOB windows keep score 0 (zero-padded k) but STAY in the softmax.
        const float rd = sqrtf((float)(di * di + dj * dj));
        const float sm = 1.f / (1.f + __expf(-5.f * (wd - rd)));
        score[w] = part * 0.08838834765f - (1.f - sm) * 10000.f;
    }

    float mx = score[0];
#pragma unroll
    for (int w = 1; w < 49; ++w) mx = fmaxf(mx, score[w]);
    float sum = 0.f;
#pragma unroll
    for (int w = 0; w < 49; ++w) {
        score[w] = __expf(score[w] - mx);
        sum += score[w];
    }
    const float inv = 1.f / sum;

    float a0 = 0.f, a1 = 0.f;
#pragma unroll
    for (int w = 0; w < 49; ++w) {
        const int di = w / 7 - 3, dj = w % 7 - 3;
        const int ii = i + di, jj = j + dj;
        const bool inb = ((unsigned)ii < 64u) && ((unsigned)jj < 64u);
        if (inb) {
            const int np = p + di * 64 + dj;
            const float a = score[w];
            a0 += a * v[np * C + lane];
            a1 += a * v[np * C + 64 + lane];
        }
    }
    y[p * C + lane]      = a0 * inv + v[p * C + lane];
    y[p * C + 64 + lane] = a1 * inv + v[p * C + 64 + lane];
}

// ---------------- Kernel 3: out = y @ W_out (M=16384, N=128, K=128) ----------------
__global__ __launch_bounds__(256) void out_kernel(const float* __restrict__ y,
                                                  const float* __restrict__ Wout,
                                                  float* __restrict__ out) {
    __shared__ float ys[16 * C];
    const int p0 = blockIdx.x * 16;
    const int tid = threadIdx.x;
    for (int e = tid; e < 16 * C; e += 256) ys[e] = y[p0 * C + e];
    __syncthreads();

    const int n = tid & 127;
    const int half = tid >> 7;  // rows 0-7 or 8-15
    float acc[8];
#pragma unroll
    for (int r = 0; r < 8; ++r) acc[r] = 0.f;

    for (int c = 0; c < C; ++c) {
        const float w = Wout[c * C + n];
#pragma unroll
        for (int r = 0; r < 8; ++r) acc[r] += ys[(half * 8 + r) * C + c] * w;
    }
#pragma unroll
    for (int r = 0; r < 8; ++r) out[(p0 + half * 8 + r) * C + n] = acc[r];
}

extern "C" void kernel_launch(void* const* d_in, const int* in_sizes, int n_in,
                              void* d_out, int out_size, void* d_ws, size_t ws_size,
                              hipStream_t stream) {
    const float* x      = (const float*)d_in[0];
    const float* Wqkv   = (const float*)d_in[1];
    const float* Wwidth = (const float*)d_in[2];
    const float* bwidth = (const float*)d_in[3];
    const float* Wout   = (const float*)d_in[4];
    float* out = (float*)d_out;

    float* q = (float*)d_ws;            // 8 MB
    float* k = q + (size_t)NPIX * C;    // 8 MB
    float* v = k + (size_t)NPIX * C;    // 8 MB
    float* y = q;  // alias: each wave reads only its own q row before writing y

    qkv_kernel<<<NPIX / 16, 384, 0, stream>>>(x, Wqkv, q, k, v);
    attn_kernel<<<NPIX / 4, 256, 0, stream>>>(x, Wwidth, bwidth, q, k, v, y);
    out_kernel<<<NPIX / 16, 256, 0, stream>>>(y, Wout, out);
}

// Round 2
// 159.337 us; speedup vs baseline: 1.1207x; 1.1207x over previous
//
#include <hip/hip_runtime.h>

#define C 128
#define NPIX 16384      // 4 * 64 * 64
#define THREE_C 384

// ---------------- Kernel 1: qkv = x @ W_qkv (M=16384, N=384, K=128) ----------------
__global__ __launch_bounds__(384) void qkv_kernel(const float* __restrict__ x,
                                                  const float* __restrict__ Wqkv,
                                                  float* __restrict__ q,
                                                  float* __restrict__ k,
                                                  float* __restrict__ v) {
    __shared__ float xs[16 * C];
    const int p0 = blockIdx.x * 16;
    const int tid = threadIdx.x;
    const float4* x4 = (const float4*)(x + (size_t)p0 * C);
    float4* xs4 = (float4*)xs;
    for (int e = tid; e < 16 * C / 4; e += 384) xs4[e] = x4[e];
    __syncthreads();

    float acc[16];
#pragma unroll
    for (int r = 0; r < 16; ++r) acc[r] = 0.f;

    const int n = tid;  // output column 0..383
    for (int c4 = 0; c4 < 32; ++c4) {
        const float w0 = Wqkv[(4 * c4 + 0) * THREE_C + n];
        const float w1 = Wqkv[(4 * c4 + 1) * THREE_C + n];
        const float w2 = Wqkv[(4 * c4 + 2) * THREE_C + n];
        const float w3 = Wqkv[(4 * c4 + 3) * THREE_C + n];
#pragma unroll
        for (int r = 0; r < 16; ++r) {
            const float4 xr = xs4[r * 32 + c4];
            acc[r] += xr.x * w0 + xr.y * w1 + xr.z * w2 + xr.w * w3;
        }
    }

    float* dst;
    int col;
    if (n < C)          { dst = q; col = n; }
    else if (n < 2 * C) { dst = k; col = n - C; }
    else                { dst = v; col = n - 2 * C; }
#pragma unroll
    for (int r = 0; r < 16; ++r) dst[(size_t)(p0 + r) * C + col] = acc[r];
}

// ---------------- Kernel 2: local attention, one wave per pixel ----------------
// Lane layout: cg = lane>>4 (channel chunk of 32), wg = lane&15 (window group).
// Slot s covers window w = wg + 16*s (valid if w < 49).
__global__ __launch_bounds__(256) void attn_kernel(const float* __restrict__ x,
                                                   const float* __restrict__ Wwidth,
                                                   const float* __restrict__ bwidth,
                                                   const float* __restrict__ q,
                                                   const float* __restrict__ k,
                                                   const float* __restrict__ v,
                                                   float* __restrict__ y) {
    const int wave = threadIdx.x >> 6;
    const int lane = threadIdx.x & 63;
    const int p = blockIdx.x * 4 + wave;
    const int i = (p >> 6) & 63;
    const int j = p & 63;
    const int cg = lane >> 4;
    const int wg = lane & 15;

    // width = sigmoid(x_row . W_width + b) * sqrt(18) + 0.5  (once per pixel)
    float wpart = x[(size_t)p * C + lane] * Wwidth[lane]
                + x[(size_t)p * C + 64 + lane] * Wwidth[64 + lane];
#pragma unroll
    for (int off = 32; off; off >>= 1) wpart += __shfl_xor(wpart, off);
    const float z = wpart + bwidth[0];
    const float wd = (1.f / (1.f + __expf(-z))) * 4.242640687f + 0.5f;

    // q chunk for this lane's 32 channels, kept in registers
    const float4* q4 = (const float4*)q;
    const float4* k4 = (const float4*)k;
    float4 qc[8];
#pragma unroll
    for (int t = 0; t < 8; ++t) qc[t] = q4[(size_t)p * 32 + cg * 8 + t];

    float sc[4];
#pragma unroll
    for (int s = 0; s < 4; ++s) {
        const int w = wg + 16 * s;
        const bool valid = (w < 49);
        int di = 0, dj = 0;
        float dot = 0.f;
        if (valid) {
            di = w / 7 - 3; dj = w % 7 - 3;
            const int ii = i + di, jj = j + dj;
            if (((unsigned)ii < 64u) && ((unsigned)jj < 64u)) {
                const int np = p + di * 64 + dj;
#pragma unroll
                for (int t = 0; t < 8; ++t) {
                    const float4 kv = k4[(size_t)np * 32 + cg * 8 + t];
                    dot += qc[t].x * kv.x + qc[t].y * kv.y + qc[t].z * kv.z + qc[t].w * kv.w;
                }
            }
        }
        // reduce the 4 channel chunks (lanes differing in bits 4,5)
        dot += __shfl_xor(dot, 16);
        dot += __shfl_xor(dot, 32);
        if (valid) {
            const float rd = sqrtf((float)(di * di + dj * dj));
            const float sm = 1.f / (1.f + __expf(-5.f * (wd - rd)));
            sc[s] = dot * 0.08838834765f - (1.f - sm) * 10000.f;
        } else {
            sc[s] = -1e30f;
        }
    }

    // softmax across 49 windows (distributed over 16-lane group x 4 slots)
    float mx = fmaxf(fmaxf(sc[0], sc[1]), fmaxf(sc[2], sc[3]));
#pragma unroll
    for (int off = 8; off; off >>= 1) mx = fmaxf(mx, __shfl_xor(mx, off));
    float e[4];
#pragma unroll
    for (int s = 0; s < 4; ++s) e[s] = __expf(sc[s] - mx);
    float lsum = e[0] + e[1] + e[2] + e[3];
#pragma unroll
    for (int off = 8; off; off >>= 1) lsum += __shfl_xor(lsum, off);
    const float inv = 1.f / lsum;

    // PV: channel-parallel (lane -> channels 2*lane, 2*lane+1), coalesced float2
    const float2* v2 = (const float2*)v;
    float ax = 0.f, ay = 0.f;
#pragma unroll
    for (int w = 0; w < 49; ++w) {
        const int di = w / 7 - 3, dj = w % 7 - 3;
        const int ii = i + di, jj = j + dj;   // wave-uniform branch
        if (((unsigned)ii < 64u) && ((unsigned)jj < 64u)) {
            const float aw = __shfl(e[w >> 4], w & 15);
            const int np = p + di * 64 + dj;
            const float2 vv = v2[(size_t)np * 64 + lane];
            ax += aw * vv.x; ay += aw * vv.y;
        }
    }
    const float2 vres = v2[(size_t)p * 64 + lane];
    float2 yo;
    yo.x = ax * inv + vres.x;
    yo.y = ay * inv + vres.y;
    ((float2*)y)[(size_t)p * 64 + lane] = yo;
}

// ---------------- Kernel 3: out = y @ W_out (M=16384, N=128, K=128) ----------------
__global__ __launch_bounds__(256) void out_kernel(const float* __restrict__ y,
                                                  const float* __restrict__ Wout,
                                                  float* __restrict__ out) {
    __shared__ float ys[16 * C];
    const int p0 = blockIdx.x * 16;
    const int tid = threadIdx.x;
    const float4* y4 = (const float4*)(y + (size_t)p0 * C);
    float4* ys4 = (float4*)ys;
    for (int e = tid; e < 16 * C / 4; e += 256) ys4[e] = y4[e];
    __syncthreads();

    const int n = tid & 127;
    const int half = tid >> 7;  // rows 0-7 or 8-15
    float acc[8];
#pragma unroll
    for (int r = 0; r < 8; ++r) acc[r] = 0.f;

    for (int c4 = 0; c4 < 32; ++c4) {
        const float w0 = Wout[(4 * c4 + 0) * C + n];
        const float w1 = Wout[(4 * c4 + 1) * C + n];
        const float w2 = Wout[(4 * c4 + 2) * C + n];
        const float w3 = Wout[(4 * c4 + 3) * C + n];
#pragma unroll
        for (int r = 0; r < 8; ++r) {
            const float4 yr = ys4[(half * 8 + r) * 32 + c4];
            acc[r] += yr.x * w0 + yr.y * w1 + yr.z * w2 + yr.w * w3;
        }
    }
#pragma unroll
    for (int r = 0; r < 8; ++r) out[(size_t)(p0 + half * 8 + r) * C + n] = acc[r];
}

extern "C" void kernel_launch(void* const* d_in, const int* in_sizes, int n_in,
                              void* d_out, int out_size, void* d_ws, size_t ws_size,
                              hipStream_t stream) {
    const float* x      = (const float*)d_in[0];
    const float* Wqkv   = (const float*)d_in[1];
    const float* Wwidth = (const float*)d_in[2];
    const float* bwidth = (const float*)d_in[3];
    const float* Wout   = (const float*)d_in[4];
    float* out = (float*)d_out;

    float* q = (float*)d_ws;            // 8 MB
    float* k = q + (size_t)NPIX * C;    // 8 MB
    float* v = k + (size_t)NPIX * C;    // 8 MB
    float* y = q;  // alias: each wave reads only its own q row before writing y

    qkv_kernel<<<NPIX / 16, 384, 0, stream>>>(x, Wqkv, q, k, v);
    attn_kernel<<<NPIX / 4, 256, 0, stream>>>(x, Wwidth, bwidth, q, k, v, y);
    out_kernel<<<NPIX / 16, 256, 0, stream>>>(y, Wout, out);
}

// Round 3
// 123.656 us; speedup vs baseline: 1.4441x; 1.2886x over previous
//
#include <hip/hip_runtime.h>

#define C 128
#define NPIX 16384      // 4 * 64 * 64
#define THREE_C 384

// ---------------- Kernel 1: qkv = x @ W_qkv (M=16384, N=384, K=128) ----------------
// 32 rows/block, 384 threads (one output column each), x rows staged in LDS.
__global__ __launch_bounds__(384) void qkv_kernel(const float* __restrict__ x,
                                                  const float* __restrict__ Wqkv,
                                                  float* __restrict__ q,
                                                  float* __restrict__ k,
                                                  float* __restrict__ v) {
    __shared__ float xs[32 * C];
    const int p0 = blockIdx.x * 32;
    const int tid = threadIdx.x;
    const float4* x4 = (const float4*)(x + (size_t)p0 * C);
    float4* xs4 = (float4*)xs;
    for (int e = tid; e < 32 * C / 4; e += 384) xs4[e] = x4[e];
    __syncthreads();

    float acc[32];
#pragma unroll
    for (int r = 0; r < 32; ++r) acc[r] = 0.f;

    const int n = tid;  // output column 0..383
    for (int c4 = 0; c4 < 32; ++c4) {
        const float w0 = Wqkv[(4 * c4 + 0) * THREE_C + n];
        const float w1 = Wqkv[(4 * c4 + 1) * THREE_C + n];
        const float w2 = Wqkv[(4 * c4 + 2) * THREE_C + n];
        const float w3 = Wqkv[(4 * c4 + 3) * THREE_C + n];
#pragma unroll
        for (int r = 0; r < 32; ++r) {
            const float4 xr = xs4[r * 32 + c4];
            acc[r] += xr.x * w0 + xr.y * w1 + xr.z * w2 + xr.w * w3;
        }
    }

    float* dst;
    int col;
    if (n < C)          { dst = q; col = n; }
    else if (n < 2 * C) { dst = k; col = n - C; }
    else                { dst = v; col = n - 2 * C; }
#pragma unroll
    for (int r = 0; r < 32; ++r) dst[(size_t)(p0 + r) * C + col] = acc[r];
}

// ---------------- Kernel 2: local attention, one wave per pixel ----------------
// QK lanes: cg = lane&3 (8 float4 each, idx t*4+cg), wg = lane>>2 (window group of 16).
// PV lanes: wsel = lane>>5 (window pair half), c4i = lane&31 (float4 channel idx).
__global__ __launch_bounds__(256) void attn_kernel(const float* __restrict__ x,
                                                   const float* __restrict__ Wwidth,
                                                   const float* __restrict__ bwidth,
                                                   const float* __restrict__ q,
                                                   const float* __restrict__ k,
                                                   const float* __restrict__ v,
                                                   float* __restrict__ y) {
    // XCD-chunked swizzle (4096 blocks, bijective): each XCD gets 512 consecutive blocks
    const int bid = ((blockIdx.x & 7) << 9) + (blockIdx.x >> 3);
    const int wave = threadIdx.x >> 6;
    const int lane = threadIdx.x & 63;
    const int p = bid * 4 + wave;
    const int i = (p >> 6) & 63;
    const int j = p & 63;
    const int cg = lane & 3;
    const int wg = lane >> 2;

    // width = sigmoid(x_row . W_width + b) * sqrt(18) + 0.5  (once per pixel)
    float wpart = x[(size_t)p * C + lane] * Wwidth[lane]
                + x[(size_t)p * C + 64 + lane] * Wwidth[64 + lane];
#pragma unroll
    for (int off = 32; off; off >>= 1) wpart += __shfl_xor(wpart, off);
    const float z = wpart + bwidth[0];
    const float wd = (1.f / (1.f + __expf(-z))) * 4.242640687f + 0.5f;

    const float4* q4 = (const float4*)q;
    const float4* k4 = (const float4*)k;
    const float4* v4 = (const float4*)v;

    // q chunk: 8 float4 at indices t*4+cg (matches k access pattern)
    float4 qc[8];
#pragma unroll
    for (int t = 0; t < 8; ++t) qc[t] = q4[(size_t)p * 32 + t * 4 + cg];

    float sc[4];
#pragma unroll
    for (int s = 0; s < 4; ++s) {
        const int w = wg + 16 * s;
        const bool valid = (w < 49);
        int di = 0, dj = 0;
        float dot = 0.f;
        if (valid) {
            di = w / 7 - 3; dj = w % 7 - 3;
            const int ii = i + di, jj = j + dj;
            if (((unsigned)ii < 64u) && ((unsigned)jj < 64u)) {
                const int np = p + di * 64 + dj;
#pragma unroll
                for (int t = 0; t < 8; ++t) {
                    const float4 kv = k4[(size_t)np * 32 + t * 4 + cg];
                    dot += qc[t].x * kv.x + qc[t].y * kv.y + qc[t].z * kv.z + qc[t].w * kv.w;
                }
            }
        }
        // reduce over cg (lane bits 0-1)
        dot += __shfl_xor(dot, 1);
        dot += __shfl_xor(dot, 2);
        if (valid) {
            const float rd = sqrtf((float)(di * di + dj * dj));
            const float sm = 1.f / (1.f + __expf(-5.f * (wd - rd)));
            sc[s] = dot * 0.08838834765f - (1.f - sm) * 10000.f;
        } else {
            sc[s] = -1e30f;
        }
    }

    // softmax across 49 windows (wg spans lane bits 2-5)
    float mx = fmaxf(fmaxf(sc[0], sc[1]), fmaxf(sc[2], sc[3]));
    mx = fmaxf(mx, __shfl_xor(mx, 4));
    mx = fmaxf(mx, __shfl_xor(mx, 8));
    mx = fmaxf(mx, __shfl_xor(mx, 16));
    mx = fmaxf(mx, __shfl_xor(mx, 32));
    float e[4];
#pragma unroll
    for (int s = 0; s < 4; ++s) e[s] = __expf(sc[s] - mx);
    float lsum = e[0] + e[1] + e[2] + e[3];
    lsum += __shfl_xor(lsum, 4);
    lsum += __shfl_xor(lsum, 8);
    lsum += __shfl_xor(lsum, 16);
    lsum += __shfl_xor(lsum, 32);
    const float inv = 1.f / lsum;

    // PV: 2 windows per iteration, one per half-wave; float4 channels
    const int wsel = lane >> 5;
    const int c4i = lane & 31;
    float4 a = make_float4(0.f, 0.f, 0.f, 0.f);
#pragma unroll
    for (int u = 0; u < 25; ++u) {
        const int w = 2 * u + wsel;               // slot u>>3 is wave-uniform
        const float aw = __shfl(e[u >> 3], ((2 * u + wsel) & 15) << 2);
        if (w < 49) {
            const int di = w / 7 - 3, dj = w % 7 - 3;
            const int ii = i + di, jj = j + dj;
            if (((unsigned)ii < 64u) && ((unsigned)jj < 64u)) {
                const int np = p + di * 64 + dj;
                const float4 vv = v4[(size_t)np * 32 + c4i];
                a.x += aw * vv.x; a.y += aw * vv.y; a.z += aw * vv.z; a.w += aw * vv.w;
            }
        }
    }
    a.x += __shfl_xor(a.x, 32);
    a.y += __shfl_xor(a.y, 32);
    a.z += __shfl_xor(a.z, 32);
    a.w += __shfl_xor(a.w, 32);

    if (lane < 32) {
        const float4 vres = v4[(size_t)p * 32 + c4i];
        float4 yo;
        yo.x = a.x * inv + vres.x;
        yo.y = a.y * inv + vres.y;
        yo.z = a.z * inv + vres.z;
        yo.w = a.w * inv + vres.w;
        ((float4*)y)[(size_t)p * 32 + c4i] = yo;
    }
}

// ---------------- Kernel 3: out = y @ W_out (M=16384, N=128, K=128) ----------------
__global__ __launch_bounds__(256) void out_kernel(const float* __restrict__ y,
                                                  const float* __restrict__ Wout,
                                                  float* __restrict__ out) {
    __shared__ float ys[32 * C];
    const int p0 = blockIdx.x * 32;
    const int tid = threadIdx.x;
    const float4* y4 = (const float4*)(y + (size_t)p0 * C);
    float4* ys4 = (float4*)ys;
    for (int e = tid; e < 32 * C / 4; e += 256) ys4[e] = y4[e];
    __syncthreads();

    const int n = tid & 127;
    const int half = tid >> 7;  // rows 0-15 or 16-31
    float acc[16];
#pragma unroll
    for (int r = 0; r < 16; ++r) acc[r] = 0.f;

    for (int c4 = 0; c4 < 32; ++c4) {
        const float w0 = Wout[(4 * c4 + 0) * C + n];
        const float w1 = Wout[(4 * c4 + 1) * C + n];
        const float w2 = Wout[(4 * c4 + 2) * C + n];
        const float w3 = Wout[(4 * c4 + 3) * C + n];
#pragma unroll
        for (int r = 0; r < 16; ++r) {
            const float4 yr = ys4[(half * 16 + r) * 32 + c4];
            acc[r] += yr.x * w0 + yr.y * w1 + yr.z * w2 + yr.w * w3;
        }
    }
#pragma unroll
    for (int r = 0; r < 16; ++r) out[(size_t)(p0 + half * 16 + r) * C + n] = acc[r];
}

extern "C" void kernel_launch(void* const* d_in, const int* in_sizes, int n_in,
                              void* d_out, int out_size, void* d_ws, size_t ws_size,
                              hipStream_t stream) {
    const float* x      = (const float*)d_in[0];
    const float* Wqkv   = (const float*)d_in[1];
    const float* Wwidth = (const float*)d_in[2];
    const float* bwidth = (const float*)d_in[3];
    const float* Wout   = (const float*)d_in[4];
    float* out = (float*)d_out;

    float* q = (float*)d_ws;            // 8 MB
    float* k = q + (size_t)NPIX * C;    // 8 MB
    float* v = k + (size_t)NPIX * C;    // 8 MB
    float* y = q;  // alias: each wave reads only its own q row before writing y

    qkv_kernel<<<NPIX / 32, 384, 0, stream>>>(x, Wqkv, q, k, v);
    attn_kernel<<<NPIX / 4, 256, 0, stream>>>(x, Wwidth, bwidth, q, k, v, y);
    out_kernel<<<NPIX / 32, 256, 0, stream>>>(y, Wout, out);
}

// Round 4
// 97.510 us; speedup vs baseline: 1.8313x; 1.2681x over previous
//
#include <hip/hip_runtime.h>

#define C 128
#define NPIX 16384      // 4 * 64 * 64
#define THREE_C 384

// ---------------- Kernel 1: qkv = x @ W_qkv (M=16384, N=384, K=128) ----------------
// Tile: 64 rows x 128 cols, K-chunks of 32. 256 threads, each 4 rows x 8 cols.
// Grid: 256 row-blocks x 3 col-blocks (nb: 0=q, 1=k, 2=v).
__global__ __launch_bounds__(256) void qkv_kernel(const float* __restrict__ x,
                                                  const float* __restrict__ Wqkv,
                                                  float* __restrict__ q,
                                                  float* __restrict__ k,
                                                  float* __restrict__ v) {
    __shared__ float xs[32][64];    // [k][row]  8 KB
    __shared__ float ws[32][128];   // [k][col] 16 KB
    const int rb = blockIdx.x / 3;
    const int nb = blockIdx.x % 3;
    const int p0 = rb * 64;
    const int tid = threadIdx.x;
    const int r0 = (tid & 15) * 4;
    const int c0 = (tid >> 4) * 8;

    float acc[4][8];
#pragma unroll
    for (int rr = 0; rr < 4; ++rr)
#pragma unroll
        for (int cc = 0; cc < 8; ++cc) acc[rr][cc] = 0.f;

    for (int k0 = 0; k0 < C; k0 += 32) {
        // stage x transposed: 64 rows x 32 k  (512 float4 loads)
        for (int f = tid; f < 512; f += 256) {
            const int r = f >> 3, k4 = f & 7;
            const float4 xv = *(const float4*)(x + (size_t)(p0 + r) * C + k0 + k4 * 4);
            xs[k4 * 4 + 0][r] = xv.x;
            xs[k4 * 4 + 1][r] = xv.y;
            xs[k4 * 4 + 2][r] = xv.z;
            xs[k4 * 4 + 3][r] = xv.w;
        }
        // stage W chunk: 32 k x 128 cols (1024 float4)
        for (int f = tid; f < 1024; f += 256) {
            const int kk = f >> 5, c4 = f & 31;
            *(float4*)&ws[kk][c4 * 4] =
                *(const float4*)(Wqkv + (size_t)(k0 + kk) * THREE_C + nb * 128 + c4 * 4);
        }
        __syncthreads();
#pragma unroll
        for (int kk = 0; kk < 32; ++kk) {
            const float4 xv = *(const float4*)&xs[kk][r0];
            const float4 wa = *(const float4*)&ws[kk][c0];
            const float4 wb = *(const float4*)&ws[kk][c0 + 4];
            const float xr[4] = {xv.x, xv.y, xv.z, xv.w};
            const float wc[8] = {wa.x, wa.y, wa.z, wa.w, wb.x, wb.y, wb.z, wb.w};
#pragma unroll
            for (int rr = 0; rr < 4; ++rr)
#pragma unroll
                for (int cc = 0; cc < 8; ++cc) acc[rr][cc] += xr[rr] * wc[cc];
        }
        __syncthreads();
    }

    float* dst = (nb == 0) ? q : (nb == 1 ? k : v);
#pragma unroll
    for (int rr = 0; rr < 4; ++rr) {
        float4 o0 = make_float4(acc[rr][0], acc[rr][1], acc[rr][2], acc[rr][3]);
        float4 o1 = make_float4(acc[rr][4], acc[rr][5], acc[rr][6], acc[rr][7]);
        *(float4*)(dst + (size_t)(p0 + r0 + rr) * C + c0) = o0;
        *(float4*)(dst + (size_t)(p0 + r0 + rr) * C + c0 + 4) = o1;
    }
}

// ---------------- Kernel 2: local attention, one wave per pixel ----------------
// QK lanes: cg = lane&3 (8 float4 each, idx t*4+cg), wg = lane>>2 (window group of 16).
// PV lanes: wsel = lane>>5 (window pair half), c4i = lane&31 (float4 channel idx).
__global__ __launch_bounds__(256) void attn_kernel(const float* __restrict__ x,
                                                   const float* __restrict__ Wwidth,
                                                   const float* __restrict__ bwidth,
                                                   const float* __restrict__ q,
                                                   const float* __restrict__ k,
                                                   const float* __restrict__ v,
                                                   float* __restrict__ y) {
    // XCD-chunked swizzle (4096 blocks, bijective): each XCD gets 512 consecutive blocks
    const int bid = ((blockIdx.x & 7) << 9) + (blockIdx.x >> 3);
    const int wave = threadIdx.x >> 6;
    const int lane = threadIdx.x & 63;
    const int p = bid * 4 + wave;
    const int i = (p >> 6) & 63;
    const int j = p & 63;
    const int cg = lane & 3;
    const int wg = lane >> 2;

    // width = sigmoid(x_row . W_width + b) * sqrt(18) + 0.5  (once per pixel)
    float wpart = x[(size_t)p * C + lane] * Wwidth[lane]
                + x[(size_t)p * C + 64 + lane] * Wwidth[64 + lane];
#pragma unroll
    for (int off = 32; off; off >>= 1) wpart += __shfl_xor(wpart, off);
    const float z = wpart + bwidth[0];
    const float wd = (1.f / (1.f + __expf(-z))) * 4.242640687f + 0.5f;

    const float4* q4 = (const float4*)q;
    const float4* k4 = (const float4*)k;
    const float4* v4 = (const float4*)v;

    // q chunk: 8 float4 at indices t*4+cg (matches k access pattern)
    float4 qc[8];
#pragma unroll
    for (int t = 0; t < 8; ++t) qc[t] = q4[(size_t)p * 32 + t * 4 + cg];

    float sc[4];
#pragma unroll
    for (int s = 0; s < 4; ++s) {
        const int w = wg + 16 * s;
        const bool valid = (w < 49);
        int di = 0, dj = 0;
        float dot = 0.f;
        if (valid) {
            di = w / 7 - 3; dj = w % 7 - 3;
            const int ii = i + di, jj = j + dj;
            if (((unsigned)ii < 64u) && ((unsigned)jj < 64u)) {
                const int np = p + di * 64 + dj;
#pragma unroll
                for (int t = 0; t < 8; ++t) {
                    const float4 kv = k4[(size_t)np * 32 + t * 4 + cg];
                    dot += qc[t].x * kv.x + qc[t].y * kv.y + qc[t].z * kv.z + qc[t].w * kv.w;
                }
            }
        }
        // reduce over cg (lane bits 0-1)
        dot += __shfl_xor(dot, 1);
        dot += __shfl_xor(dot, 2);
        if (valid) {
            const float rd = sqrtf((float)(di * di + dj * dj));
            const float sm = 1.f / (1.f + __expf(-5.f * (wd - rd)));
            sc[s] = dot * 0.08838834765f - (1.f - sm) * 10000.f;
        } else {
            sc[s] = -1e30f;
        }
    }

    // softmax across 49 windows (wg spans lane bits 2-5)
    float mx = fmaxf(fmaxf(sc[0], sc[1]), fmaxf(sc[2], sc[3]));
    mx = fmaxf(mx, __shfl_xor(mx, 4));
    mx = fmaxf(mx, __shfl_xor(mx, 8));
    mx = fmaxf(mx, __shfl_xor(mx, 16));
    mx = fmaxf(mx, __shfl_xor(mx, 32));
    float e[4];
#pragma unroll
    for (int s = 0; s < 4; ++s) e[s] = __expf(sc[s] - mx);
    float lsum = e[0] + e[1] + e[2] + e[3];
    lsum += __shfl_xor(lsum, 4);
    lsum += __shfl_xor(lsum, 8);
    lsum += __shfl_xor(lsum, 16);
    lsum += __shfl_xor(lsum, 32);
    const float inv = 1.f / lsum;

    // PV: 2 windows per iteration, one per half-wave; float4 channels
    const int wsel = lane >> 5;
    const int c4i = lane & 31;
    float4 a = make_float4(0.f, 0.f, 0.f, 0.f);
#pragma unroll
    for (int u = 0; u < 25; ++u) {
        const int w = 2 * u + wsel;               // slot u>>3 is wave-uniform
        const float aw = __shfl(e[u >> 3], ((2 * u + wsel) & 15) << 2);
        if (w < 49) {
            const int di = w / 7 - 3, dj = w % 7 - 3;
            const int ii = i + di, jj = j + dj;
            if (((unsigned)ii < 64u) && ((unsigned)jj < 64u)) {
                const int np = p + di * 64 + dj;
                const float4 vv = v4[(size_t)np * 32 + c4i];
                a.x += aw * vv.x; a.y += aw * vv.y; a.z += aw * vv.z; a.w += aw * vv.w;
            }
        }
    }
    a.x += __shfl_xor(a.x, 32);
    a.y += __shfl_xor(a.y, 32);
    a.z += __shfl_xor(a.z, 32);
    a.w += __shfl_xor(a.w, 32);

    if (lane < 32) {
        const float4 vres = v4[(size_t)p * 32 + c4i];
        float4 yo;
        yo.x = a.x * inv + vres.x;
        yo.y = a.y * inv + vres.y;
        yo.z = a.z * inv + vres.z;
        yo.w = a.w * inv + vres.w;
        ((float4*)y)[(size_t)p * 32 + c4i] = yo;
    }
}

// ---------------- Kernel 3: out = y @ W_out (M=16384, N=128, K=128) ----------------
// Tile: 32 rows x 128 cols, K-chunks of 32. 128 threads, each 4 rows x 8 cols.
__global__ __launch_bounds__(128) void out_kernel(const float* __restrict__ y,
                                                  const float* __restrict__ Wout,
                                                  float* __restrict__ out) {
    __shared__ float ys[32][32];    // [k][row]  4 KB
    __shared__ float ws[32][128];   // [k][col] 16 KB
    const int p0 = blockIdx.x * 32;
    const int tid = threadIdx.x;
    const int r0 = (tid & 7) * 4;
    const int c0 = (tid >> 3) * 8;

    float acc[4][8];
#pragma unroll
    for (int rr = 0; rr < 4; ++rr)
#pragma unroll
        for (int cc = 0; cc < 8; ++cc) acc[rr][cc] = 0.f;

    for (int k0 = 0; k0 < C; k0 += 32) {
        for (int f = tid; f < 256; f += 128) {
            const int r = f >> 3, k4 = f & 7;
            const float4 yv = *(const float4*)(y + (size_t)(p0 + r) * C + k0 + k4 * 4);
            ys[k4 * 4 + 0][r] = yv.x;
            ys[k4 * 4 + 1][r] = yv.y;
            ys[k4 * 4 + 2][r] = yv.z;
            ys[k4 * 4 + 3][r] = yv.w;
        }
        for (int f = tid; f < 1024; f += 128) {
            const int kk = f >> 5, c4 = f & 31;
            *(float4*)&ws[kk][c4 * 4] =
                *(const float4*)(Wout + (size_t)(k0 + kk) * C + c4 * 4);
        }
        __syncthreads();
#pragma unroll
        for (int kk = 0; kk < 32; ++kk) {
            const float4 yv = *(const float4*)&ys[kk][r0];
            const float4 wa = *(const float4*)&ws[kk][c0];
            const float4 wb = *(const float4*)&ws[kk][c0 + 4];
            const float yr[4] = {yv.x, yv.y, yv.z, yv.w};
            const float wc[8] = {wa.x, wa.y, wa.z, wa.w, wb.x, wb.y, wb.z, wb.w};
#pragma unroll
            for (int rr = 0; rr < 4; ++rr)
#pragma unroll
                for (int cc = 0; cc < 8; ++cc) acc[rr][cc] += yr[rr] * wc[cc];
        }
        __syncthreads();
    }

#pragma unroll
    for (int rr = 0; rr < 4; ++rr) {
        float4 o0 = make_float4(acc[rr][0], acc[rr][1], acc[rr][2], acc[rr][3]);
        float4 o1 = make_float4(acc[rr][4], acc[rr][5], acc[rr][6], acc[rr][7]);
        *(float4*)(out + (size_t)(p0 + r0 + rr) * C + c0) = o0;
        *(float4*)(out + (size_t)(p0 + r0 + rr) * C + c0 + 4) = o1;
    }
}

extern "C" void kernel_launch(void* const* d_in, const int* in_sizes, int n_in,
                              void* d_out, int out_size, void* d_ws, size_t ws_size,
                              hipStream_t stream) {
    const float* x      = (const float*)d_in[0];
    const float* Wqkv   = (const float*)d_in[1];
    const float* Wwidth = (const float*)d_in[2];
    const float* bwidth = (const float*)d_in[3];
    const float* Wout   = (const float*)d_in[4];
    float* out = (float*)d_out;

    float* q = (float*)d_ws;            // 8 MB
    float* k = q + (size_t)NPIX * C;    // 8 MB
    float* v = k + (size_t)NPIX * C;    // 8 MB
    float* y = q;  // alias: each wave reads only its own q row before writing y

    qkv_kernel<<<768, 256, 0, stream>>>(x, Wqkv, q, k, v);
    attn_kernel<<<NPIX / 4, 256, 0, stream>>>(x, Wwidth, bwidth, q, k, v, y);
    out_kernel<<<NPIX / 32, 128, 0, stream>>>(y, Wout, out);
}

// Round 5
// 86.783 us; speedup vs baseline: 2.0577x; 1.1236x over previous
//
#include <hip/hip_runtime.h>

#define C 128
#define NPIX 16384      // 4 * 64 * 64
#define THREE_C 384

typedef unsigned short u16;
typedef unsigned int u32;

__device__ __forceinline__ float bflo(u32 u) { return __uint_as_float(u << 16); }
__device__ __forceinline__ float bfhi(u32 u) { return __uint_as_float(u & 0xFFFF0000u); }
__device__ __forceinline__ u16 f2bf(float f) {
    u32 b = __float_as_uint(f);
    b += 0x7FFF + ((b >> 16) & 1);          // RNE
    return (u16)(b >> 16);
}

// ---------------- Kernel 1: qkv = x @ W_qkv (M=16384, N=384, K=128) ----------------
// Tile: 64 rows x 128 cols, K-chunks of 32. 256 threads, each 4 rows x 8 cols.
// nb: 0=q (fp32), 1=k (bf16), 2=v (bf16).
__global__ __launch_bounds__(256) void qkv_kernel(const float* __restrict__ x,
                                                  const float* __restrict__ Wqkv,
                                                  float* __restrict__ q,
                                                  u16* __restrict__ kb,
                                                  u16* __restrict__ vb) {
    __shared__ float xs[32][68];    // [k][row], padded
    __shared__ float ws[32][128];   // [k][col]
    const int rb = blockIdx.x / 3;
    const int nb = blockIdx.x % 3;
    const int p0 = rb * 64;
    const int tid = threadIdx.x;
    const int r0 = (tid & 15) * 4;
    const int c0 = (tid >> 4) * 8;

    float acc[4][8];
#pragma unroll
    for (int rr = 0; rr < 4; ++rr)
#pragma unroll
        for (int cc = 0; cc < 8; ++cc) acc[rr][cc] = 0.f;

    for (int k0 = 0; k0 < C; k0 += 32) {
        for (int f = tid; f < 512; f += 256) {
            const int r = f >> 3, k4 = f & 7;
            const float4 xv = *(const float4*)(x + (size_t)(p0 + r) * C + k0 + k4 * 4);
            xs[k4 * 4 + 0][r] = xv.x;
            xs[k4 * 4 + 1][r] = xv.y;
            xs[k4 * 4 + 2][r] = xv.z;
            xs[k4 * 4 + 3][r] = xv.w;
        }
        for (int f = tid; f < 1024; f += 256) {
            const int kk = f >> 5, c4 = f & 31;
            *(float4*)&ws[kk][c4 * 4] =
                *(const float4*)(Wqkv + (size_t)(k0 + kk) * THREE_C + nb * 128 + c4 * 4);
        }
        __syncthreads();
#pragma unroll
        for (int kk = 0; kk < 32; ++kk) {
            const float4 xv = *(const float4*)&xs[kk][r0];
            const float4 wa = *(const float4*)&ws[kk][c0];
            const float4 wb = *(const float4*)&ws[kk][c0 + 4];
            const float xr[4] = {xv.x, xv.y, xv.z, xv.w};
            const float wc[8] = {wa.x, wa.y, wa.z, wa.w, wb.x, wb.y, wb.z, wb.w};
#pragma unroll
            for (int rr = 0; rr < 4; ++rr)
#pragma unroll
                for (int cc = 0; cc < 8; ++cc) acc[rr][cc] += xr[rr] * wc[cc];
        }
        __syncthreads();
    }

    if (nb == 0) {
#pragma unroll
        for (int rr = 0; rr < 4; ++rr) {
            float4 o0 = make_float4(acc[rr][0], acc[rr][1], acc[rr][2], acc[rr][3]);
            float4 o1 = make_float4(acc[rr][4], acc[rr][5], acc[rr][6], acc[rr][7]);
            *(float4*)(q + (size_t)(p0 + r0 + rr) * C + c0) = o0;
            *(float4*)(q + (size_t)(p0 + r0 + rr) * C + c0 + 4) = o1;
        }
    } else {
        u16* dst = (nb == 1) ? kb : vb;
#pragma unroll
        for (int rr = 0; rr < 4; ++rr) {
            union { u16 us[8]; uint4 u4; } pk;
#pragma unroll
            for (int cc = 0; cc < 8; ++cc) pk.us[cc] = f2bf(acc[rr][cc]);
            *(uint4*)(dst + (size_t)(p0 + r0 + rr) * C + c0) = pk.u4;
        }
    }
}

// ---------------- Kernel 2: local attention, one wave per pixel ----------------
// QK lanes: cg = lane&3 (4 x 16B bf16 chunks), wg = lane>>2 (window group of 16).
// PV lanes: wsel = lane>>5 (window pair half), c4i = lane&31 (4-channel group).
__global__ __launch_bounds__(256) void attn_kernel(const float* __restrict__ x,
                                                   const float* __restrict__ Wwidth,
                                                   const float* __restrict__ bwidth,
                                                   const float* __restrict__ q,
                                                   const u16* __restrict__ kb,
                                                   const u16* __restrict__ vb,
                                                   float* __restrict__ y) {
    const int bid = ((blockIdx.x & 7) << 9) + (blockIdx.x >> 3);   // XCD-chunked, bijective
    const int wave = threadIdx.x >> 6;
    const int lane = threadIdx.x & 63;
    const int p = bid * 4 + wave;
    const int i = (p >> 6) & 63;
    const int j = p & 63;
    const int cg = lane & 3;
    const int wg = lane >> 2;

    // width = sigmoid(x_row . W_width + b) * sqrt(18) + 0.5
    float wpart = x[(size_t)p * C + lane] * Wwidth[lane]
                + x[(size_t)p * C + 64 + lane] * Wwidth[64 + lane];
#pragma unroll
    for (int off = 32; off; off >>= 1) wpart += __shfl_xor(wpart, off);
    const float z = wpart + bwidth[0];
    const float wd = (1.f / (1.f + __expf(-z))) * 4.242640687f + 0.5f;

    const float4* q4 = (const float4*)q;

    // q: 32 channels per lane, channels 8*(t*4+cg) .. +7
    float qc[4][8];
#pragma unroll
    for (int t = 0; t < 4; ++t) {
        const float4 qa = q4[(size_t)p * 32 + (t * 4 + cg) * 2];
        const float4 qb = q4[(size_t)p * 32 + (t * 4 + cg) * 2 + 1];
        qc[t][0] = qa.x; qc[t][1] = qa.y; qc[t][2] = qa.z; qc[t][3] = qa.w;
        qc[t][4] = qb.x; qc[t][5] = qb.y; qc[t][6] = qb.z; qc[t][7] = qb.w;
    }

    float sc[4];
#pragma unroll
    for (int s = 0; s < 4; ++s) {
        const int w = wg + 16 * s;
        const bool valid = (w < 49);
        int di = 0, dj = 0;
        float dot = 0.f;
        if (valid) {
            di = w / 7 - 3; dj = w % 7 - 3;
            const int ii = i + di, jj = j + dj;
            if (((unsigned)ii < 64u) && ((unsigned)jj < 64u)) {
                const int np = p + di * 64 + dj;
#pragma unroll
                for (int t = 0; t < 4; ++t) {
                    const uint4 kv = *(const uint4*)(kb + (size_t)np * C + (t * 4 + cg) * 8);
                    dot += qc[t][0] * bflo(kv.x) + qc[t][1] * bfhi(kv.x)
                         + qc[t][2] * bflo(kv.y) + qc[t][3] * bfhi(kv.y)
                         + qc[t][4] * bflo(kv.z) + qc[t][5] * bfhi(kv.z)
                         + qc[t][6] * bflo(kv.w) + qc[t][7] * bfhi(kv.w);
                }
            }
        }
        dot += __shfl_xor(dot, 1);
        dot += __shfl_xor(dot, 2);
        if (valid) {
            const float rd = sqrtf((float)(di * di + dj * dj));
            const float sm = 1.f / (1.f + __expf(-5.f * (wd - rd)));
            sc[s] = dot * 0.08838834765f - (1.f - sm) * 10000.f;
        } else {
            sc[s] = -1e30f;
        }
    }

    // softmax across 49 windows (wg spans lane bits 2-5)
    float mx = fmaxf(fmaxf(sc[0], sc[1]), fmaxf(sc[2], sc[3]));
    mx = fmaxf(mx, __shfl_xor(mx, 4));
    mx = fmaxf(mx, __shfl_xor(mx, 8));
    mx = fmaxf(mx, __shfl_xor(mx, 16));
    mx = fmaxf(mx, __shfl_xor(mx, 32));
    float e[4];
#pragma unroll
    for (int s = 0; s < 4; ++s) e[s] = __expf(sc[s] - mx);
    float lsum = e[0] + e[1] + e[2] + e[3];
    lsum += __shfl_xor(lsum, 4);
    lsum += __shfl_xor(lsum, 8);
    lsum += __shfl_xor(lsum, 16);
    lsum += __shfl_xor(lsum, 32);
    const float inv = 1.f / lsum;

    // PV: 2 windows per iteration (one per half-wave); 4 bf16 channels per lane
    const int wsel = lane >> 5;
    const int c4i = lane & 31;
    float4 a = make_float4(0.f, 0.f, 0.f, 0.f);
#pragma unroll
    for (int u = 0; u < 25; ++u) {
        const int w = 2 * u + wsel;
        const float aw = __shfl(e[u >> 3], ((2 * u + wsel) & 15) << 2);
        if (w < 49) {
            const int di = w / 7 - 3, dj = w % 7 - 3;
            const int ii = i + di, jj = j + dj;
            if (((unsigned)ii < 64u) && ((unsigned)jj < 64u)) {
                const int np = p + di * 64 + dj;
                const uint2 vv = *(const uint2*)(vb + (size_t)np * C + c4i * 4);
                a.x += aw * bflo(vv.x); a.y += aw * bfhi(vv.x);
                a.z += aw * bflo(vv.y); a.w += aw * bfhi(vv.y);
            }
        }
    }
    a.x += __shfl_xor(a.x, 32);
    a.y += __shfl_xor(a.y, 32);
    a.z += __shfl_xor(a.z, 32);
    a.w += __shfl_xor(a.w, 32);

    if (lane < 32) {
        const uint2 vr = *(const uint2*)(vb + (size_t)p * C + c4i * 4);
        float4 yo;
        yo.x = a.x * inv + bflo(vr.x);
        yo.y = a.y * inv + bfhi(vr.x);
        yo.z = a.z * inv + bflo(vr.y);
        yo.w = a.w * inv + bfhi(vr.y);
        *(float4*)(y + (size_t)p * C + c4i * 4) = yo;
    }
}

// ---------------- Kernel 3: out = y @ W_out (M=16384, N=128, K=128) ----------------
// Tile: 16 rows x 128 cols, K-chunks of 32. 128 threads, each 2 rows x 8 cols. Grid 1024.
__global__ __launch_bounds__(128) void out_kernel(const float* __restrict__ y,
                                                  const float* __restrict__ Wout,
                                                  float* __restrict__ out) {
    __shared__ float ys[32][18];    // [k][row], padded
    __shared__ float ws[32][128];   // [k][col]
    const int p0 = blockIdx.x * 16;
    const int tid = threadIdx.x;
    const int r0 = (tid & 7) * 2;
    const int c0 = (tid >> 3) * 8;

    float acc[2][8];
#pragma unroll
    for (int rr = 0; rr < 2; ++rr)
#pragma unroll
        for (int cc = 0; cc < 8; ++cc) acc[rr][cc] = 0.f;

    for (int k0 = 0; k0 < C; k0 += 32) {
        {
            const int r = tid >> 3, k4 = tid & 7;   // 128 threads = 128 float4
            const float4 yv = *(const float4*)(y + (size_t)(p0 + r) * C + k0 + k4 * 4);
            ys[k4 * 4 + 0][r] = yv.x;
            ys[k4 * 4 + 1][r] = yv.y;
            ys[k4 * 4 + 2][r] = yv.z;
            ys[k4 * 4 + 3][r] = yv.w;
        }
        for (int f = tid; f < 1024; f += 128) {
            const int kk = f >> 5, c4 = f & 31;
            *(float4*)&ws[kk][c4 * 4] =
                *(const float4*)(Wout + (size_t)(k0 + kk) * C + c4 * 4);
        }
        __syncthreads();
#pragma unroll
        for (int kk = 0; kk < 32; ++kk) {
            const float2 yv = *(const float2*)&ys[kk][r0];
            const float4 wa = *(const float4*)&ws[kk][c0];
            const float4 wb = *(const float4*)&ws[kk][c0 + 4];
            const float yr[2] = {yv.x, yv.y};
            const float wc[8] = {wa.x, wa.y, wa.z, wa.w, wb.x, wb.y, wb.z, wb.w};
#pragma unroll
            for (int rr = 0; rr < 2; ++rr)
#pragma unroll
                for (int cc = 0; cc < 8; ++cc) acc[rr][cc] += yr[rr] * wc[cc];
        }
        __syncthreads();
    }

#pragma unroll
    for (int rr = 0; rr < 2; ++rr) {
        float4 o0 = make_float4(acc[rr][0], acc[rr][1], acc[rr][2], acc[rr][3]);
        float4 o1 = make_float4(acc[rr][4], acc[rr][5], acc[rr][6], acc[rr][7]);
        *(float4*)(out + (size_t)(p0 + r0 + rr) * C + c0) = o0;
        *(float4*)(out + (size_t)(p0 + r0 + rr) * C + c0 + 4) = o1;
    }
}

extern "C" void kernel_launch(void* const* d_in, const int* in_sizes, int n_in,
                              void* d_out, int out_size, void* d_ws, size_t ws_size,
                              hipStream_t stream) {
    const float* x      = (const float*)d_in[0];
    const float* Wqkv   = (const float*)d_in[1];
    const float* Wwidth = (const float*)d_in[2];
    const float* bwidth = (const float*)d_in[3];
    const float* Wout   = (const float*)d_in[4];
    float* out = (float*)d_out;

    float* q = (float*)d_ws;                       // 8 MB fp32
    u16* kb  = (u16*)(q + (size_t)NPIX * C);       // 4 MB bf16
    u16* vb  = kb + (size_t)NPIX * C;              // 4 MB bf16
    float* y = q;   // alias: each wave reads only its own q row before writing y

    qkv_kernel<<<768, 256, 0, stream>>>(x, Wqkv, q, kb, vb);
    attn_kernel<<<NPIX / 4, 256, 0, stream>>>(x, Wwidth, bwidth, q, kb, vb, y);
    out_kernel<<<NPIX / 16, 128, 0, stream>>>(y, Wout, out);
}

// Round 6
// 76.235 us; speedup vs baseline: 2.3424x; 1.1384x over previous
//
#include <hip/hip_runtime.h>

#define C 128
#define NPIX 16384      // 4 * 64 * 64
#define THREE_C 384

typedef unsigned short u16;
typedef unsigned int u32;
typedef short bf16x8 __attribute__((ext_vector_type(8)));
typedef float f32x4 __attribute__((ext_vector_type(4)));

__device__ __forceinline__ float bf2f(u16 h) { return __uint_as_float(((u32)h) << 16); }
__device__ __forceinline__ u16 f2bf(float f) {
    u32 b = __float_as_uint(f);
    b += 0x7FFF + ((b >> 16) & 1);          // RNE
    return (u16)(b >> 16);
}

// ---------------- Kernel 1: qkv = x @ W_qkv, all outputs bf16; + width ----------------
// Tile: 64 rows x 128 cols, K-chunks of 32. 256 threads, each 4 rows x 8 cols.
// nb: 0=q, 1=k, 2=v. nb==0 blocks also compute width = sigmoid(x@W_width+b)*maxd+0.5.
__global__ __launch_bounds__(256) void qkv_kernel(const float* __restrict__ x,
                                                  const float* __restrict__ Wqkv,
                                                  const float* __restrict__ Wwidth,
                                                  const float* __restrict__ bwidth,
                                                  u16* __restrict__ qb,
                                                  u16* __restrict__ kb,
                                                  u16* __restrict__ vb,
                                                  float* __restrict__ width_g) {
    __shared__ float xs[32][68];    // [k][row], padded
    __shared__ float ws[32][128];   // [k][col]
    const int rb = blockIdx.x / 3;
    const int nb = blockIdx.x % 3;
    const int p0 = rb * 64;
    const int tid = threadIdx.x;
    const int r0 = (tid & 15) * 4;
    const int c0 = (tid >> 4) * 8;

    float acc[4][8];
#pragma unroll
    for (int rr = 0; rr < 4; ++rr)
#pragma unroll
        for (int cc = 0; cc < 8; ++cc) acc[rr][cc] = 0.f;

    float wacc = 0.f;

    for (int k0 = 0; k0 < C; k0 += 32) {
        for (int f = tid; f < 512; f += 256) {
            const int r = f >> 3, k4 = f & 7;
            const float4 xv = *(const float4*)(x + (size_t)(p0 + r) * C + k0 + k4 * 4);
            xs[k4 * 4 + 0][r] = xv.x;
            xs[k4 * 4 + 1][r] = xv.y;
            xs[k4 * 4 + 2][r] = xv.z;
            xs[k4 * 4 + 3][r] = xv.w;
        }
        for (int f = tid; f < 1024; f += 256) {
            const int kk = f >> 5, c4 = f & 31;
            *(float4*)&ws[kk][c4 * 4] =
                *(const float4*)(Wqkv + (size_t)(k0 + kk) * THREE_C + nb * 128 + c4 * 4);
        }
        __syncthreads();
        if (nb == 0 && tid < 64) {
#pragma unroll
            for (int kk = 0; kk < 32; ++kk) wacc += xs[kk][tid] * Wwidth[k0 + kk];
        }
#pragma unroll
        for (int kk = 0; kk < 32; ++kk) {
            const float4 xv = *(const float4*)&xs[kk][r0];
            const float4 wa = *(const float4*)&ws[kk][c0];
            const float4 wb = *(const float4*)&ws[kk][c0 + 4];
            const float xr[4] = {xv.x, xv.y, xv.z, xv.w};
            const float wc[8] = {wa.x, wa.y, wa.z, wa.w, wb.x, wb.y, wb.z, wb.w};
#pragma unroll
            for (int rr = 0; rr < 4; ++rr)
#pragma unroll
                for (int cc = 0; cc < 8; ++cc) acc[rr][cc] += xr[rr] * wc[cc];
        }
        __syncthreads();
    }

    u16* dst = (nb == 0) ? qb : (nb == 1) ? kb : vb;
#pragma unroll
    for (int rr = 0; rr < 4; ++rr) {
        union { u16 us[8]; uint4 u4; } pk;
#pragma unroll
        for (int cc = 0; cc < 8; ++cc) pk.us[cc] = f2bf(acc[rr][cc]);
        *(uint4*)(dst + (size_t)(p0 + r0 + rr) * C + c0) = pk.u4;
    }
    if (nb == 0 && tid < 64) {
        const float z = wacc + bwidth[0];
        width_g[p0 + tid] = (1.f / (1.f + __expf(-z))) * 4.242640687f + 0.5f;
    }
}

// ---------------- Kernel 2: MFMA tile attention ----------------
// One block per 8x8 pixel tile (256 blocks, 512 threads = 8 waves).
// Halo 14x14 = 196 positions, N padded to 208 (13 frags), PV-K padded to 224.
// LDS: K_halo [208][136] row-major(chan-padded); V^T [128][232]; P [64][232].
#define HSTRIDE 136
#define TSTRIDE 232

__global__ __launch_bounds__(512) void attn_kernel(const u16* __restrict__ qb,
                                                   const u16* __restrict__ kb,
                                                   const u16* __restrict__ vb,
                                                   const float* __restrict__ width_g,
                                                   float* __restrict__ y) {
    __shared__ u16 Kl[208 * HSTRIDE];   // 56576 B
    __shared__ u16 Vt[128 * TSTRIDE];   // 59392 B
    __shared__ u16 Pl[64 * TSTRIDE];    // 29696 B
    __shared__ float rmax[2][64];
    __shared__ float rsum[2][64];
    __shared__ float wdl[64];

    const int tid = threadIdx.x;
    const int wv = tid >> 6;
    const int l = tid & 63;
    const int l15 = l & 15;
    const int l4 = l >> 4;

    // XCD-chunked work id: 32 consecutive tiles per XCD for halo L2 sharing
    const int W = ((int)blockIdx.x & 7) * 32 + ((int)blockIdx.x >> 3);
    const int b = W >> 6;
    const int t = W & 63;
    const int i0 = (t >> 3) * 8;
    const int j0 = (t & 7) * 8;
    const int pbase = b * 4096;

    // ---- phase 0a: zero LDS (OOB halo rows / pad columns must be 0) ----
    {
        const uint4 z4 = make_uint4(0, 0, 0, 0);
        uint4* a0 = (uint4*)Kl;
        for (int f = tid; f < 3536; f += 512) a0[f] = z4;
        uint4* a1 = (uint4*)Vt;
        for (int f = tid; f < 3712; f += 512) a1[f] = z4;
        uint4* a2 = (uint4*)Pl;
        for (int f = tid; f < 1856; f += 512) a2[f] = z4;
        if (tid < 64)
            wdl[tid] = width_g[pbase + (i0 + (tid >> 3)) * 64 + j0 + (tid & 7)];
    }
    __syncthreads();  // B0: memset before staged writes

    // ---- phase 0b: stage K halo (row-major) and V halo (transposed) ----
    for (int f = tid; f < 3328; f += 512) {      // 208*16 chunk tasks
        const int c = f & 15, h = f >> 4;
        if (h < 196) {
            const int hi = (h * 2341) >> 15;     // h / 14
            const int hj = h - hi * 14;
            const int ii = i0 - 3 + hi, jj = j0 - 3 + hj;
            if (((unsigned)ii < 64u) && ((unsigned)jj < 64u)) {
                const int ps = pbase + ii * 64 + jj;
                *(uint4*)&Kl[h * HSTRIDE + c * 8] = *(const uint4*)(kb + (size_t)ps * C + c * 8);
            }
        }
    }
    for (int f = tid; f < 3328; f += 512) {
        const int c8 = f & 15, h = f >> 4;
        if (h < 196) {
            const int hi = (h * 2341) >> 15;
            const int hj = h - hi * 14;
            const int ii = i0 - 3 + hi, jj = j0 - 3 + hj;
            if (((unsigned)ii < 64u) && ((unsigned)jj < 64u)) {
                const int ps = pbase + ii * 64 + jj;
                union { uint4 u4; u16 us[8]; } kv;
                kv.u4 = *(const uint4*)(vb + (size_t)ps * C + c8 * 8);
#pragma unroll
                for (int s = 0; s < 8; ++s) {
                    const int cc = (s + c8) & 7;             // rotate to avoid bank clash
                    Vt[(c8 * 8 + cc) * TSTRIDE + h] = kv.us[cc];
                }
            }
        }
    }

    // Q A-fragments direct from global (row = l15, k = kf*32 + l4*8)
    const int strip = wv >> 1;                    // M-strip 0..3 (16 q rows each)
    const int nfpar = wv & 1;
    bf16x8 qf[4];
    {
        const int qr = strip * 16 + l15;
        const int p = pbase + (i0 + (qr >> 3)) * 64 + j0 + (qr & 7);
#pragma unroll
        for (int kf = 0; kf < 4; ++kf)
            qf[kf] = *(const bf16x8*)(qb + (size_t)p * C + kf * 32 + l4 * 8);
    }
    __syncthreads();  // B1

    // ---- QK^T: each wave: its strip x nf = nfpar + 2*tt ----
    f32x4 sv[7];
#pragma unroll
    for (int tt = 0; tt < 7; ++tt) {
        const int nf = nfpar + 2 * tt;
        f32x4 acc = {0.f, 0.f, 0.f, 0.f};
        if (nf < 13) {
            const u16* kr = Kl + (nf * 16 + l15) * HSTRIDE + l4 * 8;
#pragma unroll
            for (int kf = 0; kf < 4; ++kf)
                acc = __builtin_amdgcn_mfma_f32_16x16x32_bf16(
                    qf[kf], *(const bf16x8*)(kr + kf * 32), acc, 0, 0, 0);
        }
        sv[tt] = acc;
    }

    // ---- mask + penalty + partial row-max ----
    const int qrb = strip * 16 + l4 * 4;
    float wdr[4], mxr[4];
#pragma unroll
    for (int r = 0; r < 4; ++r) { wdr[r] = wdl[qrb + r]; mxr[r] = -3.0e38f; }
#pragma unroll
    for (int tt = 0; tt < 7; ++tt) {
        const int nf = nfpar + 2 * tt;
        if (nf < 13) {
            const int n = nf * 16 + l15;
            const int hi = (n * 2341) >> 15;
            const int hj = n - hi * 14;
#pragma unroll
            for (int r = 0; r < 4; ++r) {
                const int qr = qrb + r;
                const int di = hi - 3 - (qr >> 3);
                const int dj = hj - 3 - (qr & 7);
                const bool valid = ((unsigned)(di + 3) <= 6u) && ((unsigned)(dj + 3) <= 6u);
                float s = -3.0e38f;
                if (valid) {
                    const float rd = sqrtf((float)(di * di + dj * dj));
                    const float sm = 1.f / (1.f + __expf(-5.f * (wdr[r] - rd)));
                    s = sv[tt][r] * 0.08838834765f - (1.f - sm) * 10000.f;
                }
                sv[tt][r] = s;
                mxr[r] = fmaxf(mxr[r], s);
            }
        } else {
#pragma unroll
            for (int r = 0; r < 4; ++r) sv[tt][r] = -3.0e38f;
        }
    }
#pragma unroll
    for (int r = 0; r < 4; ++r) {
        float m = mxr[r];
        m = fmaxf(m, __shfl_xor(m, 1));
        m = fmaxf(m, __shfl_xor(m, 2));
        m = fmaxf(m, __shfl_xor(m, 4));
        m = fmaxf(m, __shfl_xor(m, 8));
        mxr[r] = m;
    }
    if (l15 == 0) {
#pragma unroll
        for (int r = 0; r < 4; ++r) rmax[nfpar][qrb + r] = mxr[r];
    }
    __syncthreads();  // B2

    // ---- exp + partial row-sum ----
    float mfin[4], smr[4];
#pragma unroll
    for (int r = 0; r < 4; ++r) {
        mfin[r] = fmaxf(rmax[0][qrb + r], rmax[1][qrb + r]);
        smr[r] = 0.f;
    }
#pragma unroll
    for (int tt = 0; tt < 7; ++tt) {
#pragma unroll
        for (int r = 0; r < 4; ++r) {
            const float e = __expf(sv[tt][r] - mfin[r]);
            sv[tt][r] = e;
            smr[r] += e;
        }
    }
#pragma unroll
    for (int r = 0; r < 4; ++r) {
        float s = smr[r];
        s += __shfl_xor(s, 1);
        s += __shfl_xor(s, 2);
        s += __shfl_xor(s, 4);
        s += __shfl_xor(s, 8);
        smr[r] = s;
    }
    if (l15 == 0) {
#pragma unroll
        for (int r = 0; r < 4; ++r) rsum[nfpar][qrb + r] = smr[r];
    }
    __syncthreads();  // B3

    // ---- normalize + write P (bf16) ----
    float invr[4];
#pragma unroll
    for (int r = 0; r < 4; ++r) invr[r] = 1.f / (rsum[0][qrb + r] + rsum[1][qrb + r]);
#pragma unroll
    for (int tt = 0; tt < 7; ++tt) {
        const int nf = nfpar + 2 * tt;
        if (nf < 13) {
            const int n = nf * 16 + l15;
#pragma unroll
            for (int r = 0; r < 4; ++r)
                Pl[(qrb + r) * TSTRIDE + n] = f2bf(sv[tt][r] * invr[r]);
        }
    }
    __syncthreads();  // B4

    // ---- PV: O = P @ V, K = 224 (7 frags); wave: strip x channel-half ----
    const int nh = wv & 1;
    f32x4 oacc[4];
#pragma unroll
    for (int nf2 = 0; nf2 < 4; ++nf2) oacc[nf2] = (f32x4){0.f, 0.f, 0.f, 0.f};
#pragma unroll
    for (int kf = 0; kf < 7; ++kf) {
        const bf16x8 pa = *(const bf16x8*)(Pl + (strip * 16 + l15) * TSTRIDE + kf * 32 + l4 * 8);
#pragma unroll
        for (int nf2 = 0; nf2 < 4; ++nf2) {
            const bf16x8 vf = *(const bf16x8*)(Vt + (nh * 64 + nf2 * 16 + l15) * TSTRIDE + kf * 32 + l4 * 8);
            oacc[nf2] = __builtin_amdgcn_mfma_f32_16x16x32_bf16(pa, vf, oacc[nf2], 0, 0, 0);
        }
    }
    // epilogue: y = O + v  (fp32)
#pragma unroll
    for (int nf2 = 0; nf2 < 4; ++nf2) {
        const int cch = nh * 64 + nf2 * 16 + l15;
#pragma unroll
        for (int r = 0; r < 4; ++r) {
            const int qr = qrb + r;
            const int p = pbase + (i0 + (qr >> 3)) * 64 + j0 + (qr & 7);
            y[(size_t)p * C + cch] = oacc[nf2][r] + bf2f(vb[(size_t)p * C + cch]);
        }
    }
}

// ---------------- Kernel 3: out = y @ W_out (M=16384, N=128, K=128) ----------------
__global__ __launch_bounds__(128) void out_kernel(const float* __restrict__ y,
                                                  const float* __restrict__ Wout,
                                                  float* __restrict__ out) {
    __shared__ float ys[32][18];
    __shared__ float ws[32][128];
    const int p0 = blockIdx.x * 16;
    const int tid = threadIdx.x;
    const int r0 = (tid & 7) * 2;
    const int c0 = (tid >> 3) * 8;

    float acc[2][8];
#pragma unroll
    for (int rr = 0; rr < 2; ++rr)
#pragma unroll
        for (int cc = 0; cc < 8; ++cc) acc[rr][cc] = 0.f;

    for (int k0 = 0; k0 < C; k0 += 32) {
        {
            const int r = tid >> 3, k4 = tid & 7;
            const float4 yv = *(const float4*)(y + (size_t)(p0 + r) * C + k0 + k4 * 4);
            ys[k4 * 4 + 0][r] = yv.x;
            ys[k4 * 4 + 1][r] = yv.y;
            ys[k4 * 4 + 2][r] = yv.z;
            ys[k4 * 4 + 3][r] = yv.w;
        }
        for (int f = tid; f < 1024; f += 128) {
            const int kk = f >> 5, c4 = f & 31;
            *(float4*)&ws[kk][c4 * 4] =
                *(const float4*)(Wout + (size_t)(k0 + kk) * C + c4 * 4);
        }
        __syncthreads();
#pragma unroll
        for (int kk = 0; kk < 32; ++kk) {
            const float2 yv = *(const float2*)&ys[kk][r0];
            const float4 wa = *(const float4*)&ws[kk][c0];
            const float4 wb = *(const float4*)&ws[kk][c0 + 4];
            const float yr[2] = {yv.x, yv.y};
            const float wc[8] = {wa.x, wa.y, wa.z, wa.w, wb.x, wb.y, wb.z, wb.w};
#pragma unroll
            for (int rr = 0; rr < 2; ++rr)
#pragma unroll
                for (int cc = 0; cc < 8; ++cc) acc[rr][cc] += yr[rr] * wc[cc];
        }
        __syncthreads();
    }

#pragma unroll
    for (int rr = 0; rr < 2; ++rr) {
        float4 o0 = make_float4(acc[rr][0], acc[rr][1], acc[rr][2], acc[rr][3]);
        float4 o1 = make_float4(acc[rr][4], acc[rr][5], acc[rr][6], acc[rr][7]);
        *(float4*)(out + (size_t)(p0 + r0 + rr) * C + c0) = o0;
        *(float4*)(out + (size_t)(p0 + r0 + rr) * C + c0 + 4) = o1;
    }
}

extern "C" void kernel_launch(void* const* d_in, const int* in_sizes, int n_in,
                              void* d_out, int out_size, void* d_ws, size_t ws_size,
                              hipStream_t stream) {
    const float* x      = (const float*)d_in[0];
    const float* Wqkv   = (const float*)d_in[1];
    const float* Wwidth = (const float*)d_in[2];
    const float* bwidth = (const float*)d_in[3];
    const float* Wout   = (const float*)d_in[4];
    float* out = (float*)d_out;

    u16* qb = (u16*)d_ws;                           // 4 MB bf16
    u16* kb = qb + (size_t)NPIX * C;                // 4 MB bf16
    u16* vb = kb + (size_t)NPIX * C;                // 4 MB bf16
    float* width = (float*)(vb + (size_t)NPIX * C); // 64 KB fp32
    float* y = width + NPIX;                        // 8 MB fp32

    qkv_kernel<<<768, 256, 0, stream>>>(x, Wqkv, Wwidth, bwidth, qb, kb, vb, width);
    attn_kernel<<<256, 512, 0, stream>>>(qb, kb, vb, width, y);
    out_kernel<<<NPIX / 16, 128, 0, stream>>>(y, Wout, out);
}

// Round 7
// 55.353 us; speedup vs baseline: 3.2260x; 1.3772x over previous
//
#include <hip/hip_runtime.h>

#define C 128
#define NPIX 16384      // 4 * 64 * 64
#define THREE_C 384

typedef unsigned short u16;
typedef unsigned int u32;
typedef short bf16x8 __attribute__((ext_vector_type(8)));
typedef float f32x4 __attribute__((ext_vector_type(4)));

__device__ __forceinline__ float bf2f(u16 h) { return __uint_as_float(((u32)h) << 16); }
__device__ __forceinline__ u16 f2bf(float f) {
    u32 b = __float_as_uint(f);
    b += 0x7FFF + ((b >> 16) & 1);          // RNE
    return (u16)(b >> 16);
}
__device__ __forceinline__ u32 pack2(float a, float b) {
    return (u32)f2bf(a) | ((u32)f2bf(b) << 16);
}

// ---------------- Kernel 1: qkv = x @ W_qkv via MFMA (M=16384, N=384, K=128) ----------------
// Grid 768 = 256 row-tiles x 3 (nb: 0=q,1=k,2=v). 256 thr = 4 waves, each a 16-row strip.
// LDS: xs [64][136] bf16, wt [128][136] bf16 (W transposed: [col][k]).
#define GST 136

__global__ __launch_bounds__(256) void qkv_kernel(const float* __restrict__ x,
                                                  const float* __restrict__ Wqkv,
                                                  const float* __restrict__ Wwidth,
                                                  const float* __restrict__ bwidth,
                                                  u16* __restrict__ qb,
                                                  u16* __restrict__ kb,
                                                  u16* __restrict__ vb,
                                                  float* __restrict__ width_g) {
    __shared__ u16 xs[64 * GST];
    __shared__ u16 wt[128 * GST];
    const int rb = blockIdx.x / 3;
    const int nb = blockIdx.x % 3;
    const int p0 = rb * 64;
    const int tid = threadIdx.x;
    const int wv = tid >> 6;
    const int l = tid & 63;
    const int l15 = l & 15;
    const int l4 = l >> 4;

    // stage x rows (bf16): 64 rows x 32 k-quads
    for (int f = tid; f < 2048; f += 256) {
        const int kq = f & 31, r = f >> 5;
        const float4 xv = *(const float4*)(x + (size_t)(p0 + r) * C + kq * 4);
        uint2 pk;
        pk.x = pack2(xv.x, xv.y);
        pk.y = pack2(xv.z, xv.w);
        *(uint2*)&xs[r * GST + kq * 4] = pk;
    }
    // stage W transposed (bf16): 128 cols x 32 k-quads
    for (int f = tid; f < 4096; f += 256) {
        const int c = f & 127, kq = f >> 7;
        const float w0 = Wqkv[(size_t)(kq * 4 + 0) * THREE_C + nb * 128 + c];
        const float w1 = Wqkv[(size_t)(kq * 4 + 1) * THREE_C + nb * 128 + c];
        const float w2 = Wqkv[(size_t)(kq * 4 + 2) * THREE_C + nb * 128 + c];
        const float w3 = Wqkv[(size_t)(kq * 4 + 3) * THREE_C + nb * 128 + c];
        uint2 pk;
        pk.x = pack2(w0, w1);
        pk.y = pack2(w2, w3);
        *(uint2*)&wt[c * GST + kq * 4] = pk;
    }
    __syncthreads();

    // width (nb==0 blocks): sigmoid(x . W_width + b) * maxd + 0.5
    if (nb == 0 && tid < 64) {
        float wacc = 0.f;
#pragma unroll
        for (int kk = 0; kk < C; ++kk) wacc += bf2f(xs[tid * GST + kk]) * Wwidth[kk];
        const float z = wacc + bwidth[0];
        width_g[p0 + tid] = (1.f / (1.f + __expf(-z))) * 4.242640687f + 0.5f;
    }

    const int strip = wv * 16;
    bf16x8 af[4];
#pragma unroll
    for (int kf = 0; kf < 4; ++kf)
        af[kf] = *(const bf16x8*)&xs[(strip + l15) * GST + kf * 32 + l4 * 8];

    f32x4 acc[8];
#pragma unroll
    for (int nf = 0; nf < 8; ++nf) acc[nf] = (f32x4){0.f, 0.f, 0.f, 0.f};
#pragma unroll
    for (int nf = 0; nf < 8; ++nf) {
#pragma unroll
        for (int kf = 0; kf < 4; ++kf) {
            const bf16x8 bf = *(const bf16x8*)&wt[(nf * 16 + l15) * GST + kf * 32 + l4 * 8];
            acc[nf] = __builtin_amdgcn_mfma_f32_16x16x32_bf16(af[kf], bf, acc[nf], 0, 0, 0);
        }
    }

    u16* dst = (nb == 0) ? qb : (nb == 1) ? kb : vb;
#pragma unroll
    for (int nf = 0; nf < 8; ++nf) {
        const int col = nf * 16 + l15;
#pragma unroll
        for (int r = 0; r < 4; ++r) {
            const int row = strip + l4 * 4 + r;
            dst[(size_t)(p0 + row) * C + col] = f2bf(acc[nf][r]);
        }
    }
}

// ---------------- Kernel 2: MFMA tile attention ----------------
// One block per 8x8 pixel tile (256 blocks, 512 threads = 8 waves).
// Halo 14x14 = 196 positions, N padded to 208 (13 frags), PV-K padded to 224.
#define HSTRIDE 136
#define TSTRIDE 232

__global__ __launch_bounds__(512) void attn_kernel(const u16* __restrict__ qb,
                                                   const u16* __restrict__ kb,
                                                   const u16* __restrict__ vb,
                                                   const float* __restrict__ width_g,
                                                   u16* __restrict__ y) {
    __shared__ u16 Kl[208 * HSTRIDE];   // 56576 B
    __shared__ u16 Vt[128 * TSTRIDE];   // 59392 B
    __shared__ u16 Pl[64 * TSTRIDE];    // 29696 B
    __shared__ float rmax[2][64];
    __shared__ float rsum[2][64];
    __shared__ float wdl[64];

    const int tid = threadIdx.x;
    const int wv = tid >> 6;
    const int l = tid & 63;
    const int l15 = l & 15;
    const int l4 = l >> 4;

    const int W = ((int)blockIdx.x & 7) * 32 + ((int)blockIdx.x >> 3);
    const int b = W >> 6;
    const int t = W & 63;
    const int i0 = (t >> 3) * 8;
    const int j0 = (t & 7) * 8;
    const int pbase = b * 4096;

    {
        const uint4 z4 = make_uint4(0, 0, 0, 0);
        uint4* a0 = (uint4*)Kl;
        for (int f = tid; f < 3536; f += 512) a0[f] = z4;
        uint4* a1 = (uint4*)Vt;
        for (int f = tid; f < 3712; f += 512) a1[f] = z4;
        uint4* a2 = (uint4*)Pl;
        for (int f = tid; f < 1856; f += 512) a2[f] = z4;
        if (tid < 64)
            wdl[tid] = width_g[pbase + (i0 + (tid >> 3)) * 64 + j0 + (tid & 7)];
    }
    __syncthreads();  // B0

    for (int f = tid; f < 3328; f += 512) {
        const int c = f & 15, h = f >> 4;
        if (h < 196) {
            const int hi = (h * 2341) >> 15;
            const int hj = h - hi * 14;
            const int ii = i0 - 3 + hi, jj = j0 - 3 + hj;
            if (((unsigned)ii < 64u) && ((unsigned)jj < 64u)) {
                const int ps = pbase + ii * 64 + jj;
                *(uint4*)&Kl[h * HSTRIDE + c * 8] = *(const uint4*)(kb + (size_t)ps * C + c * 8);
            }
        }
    }
    for (int f = tid; f < 3328; f += 512) {
        const int c8 = f & 15, h = f >> 4;
        if (h < 196) {
            const int hi = (h * 2341) >> 15;
            const int hj = h - hi * 14;
            const int ii = i0 - 3 + hi, jj = j0 - 3 + hj;
            if (((unsigned)ii < 64u) && ((unsigned)jj < 64u)) {
                const int ps = pbase + ii * 64 + jj;
                union { uint4 u4; u16 us[8]; } kv;
                kv.u4 = *(const uint4*)(vb + (size_t)ps * C + c8 * 8);
#pragma unroll
                for (int s = 0; s < 8; ++s) {
                    const int cc = (s + c8) & 7;
                    Vt[(c8 * 8 + cc) * TSTRIDE + h] = kv.us[cc];
                }
            }
        }
    }

    const int strip = wv >> 1;
    const int nfpar = wv & 1;
    bf16x8 qf[4];
    {
        const int qr = strip * 16 + l15;
        const int p = pbase + (i0 + (qr >> 3)) * 64 + j0 + (qr & 7);
#pragma unroll
        for (int kf = 0; kf < 4; ++kf)
            qf[kf] = *(const bf16x8*)(qb + (size_t)p * C + kf * 32 + l4 * 8);
    }
    __syncthreads();  // B1

    f32x4 sv[7];
#pragma unroll
    for (int tt = 0; tt < 7; ++tt) {
        const int nf = nfpar + 2 * tt;
        f32x4 acc = {0.f, 0.f, 0.f, 0.f};
        if (nf < 13) {
            const u16* kr = Kl + (nf * 16 + l15) * HSTRIDE + l4 * 8;
#pragma unroll
            for (int kf = 0; kf < 4; ++kf)
                acc = __builtin_amdgcn_mfma_f32_16x16x32_bf16(
                    qf[kf], *(const bf16x8*)(kr + kf * 32), acc, 0, 0, 0);
        }
        sv[tt] = acc;
    }

    const int qrb = strip * 16 + l4 * 4;
    float wdr[4], mxr[4];
#pragma unroll
    for (int r = 0; r < 4; ++r) { wdr[r] = wdl[qrb + r]; mxr[r] = -3.0e38f; }
#pragma unroll
    for (int tt = 0; tt < 7; ++tt) {
        const int nf = nfpar + 2 * tt;
        if (nf < 13) {
            const int n = nf * 16 + l15;
            const int hi = (n * 2341) >> 15;
            const int hj = n - hi * 14;
#pragma unroll
            for (int r = 0; r < 4; ++r) {
                const int qr = qrb + r;
                const int di = hi - 3 - (qr >> 3);
                const int dj = hj - 3 - (qr & 7);
                const bool valid = ((unsigned)(di + 3) <= 6u) && ((unsigned)(dj + 3) <= 6u);
                float s = -3.0e38f;
                if (valid) {
                    const float rd = sqrtf((float)(di * di + dj * dj));
                    const float sm = 1.f / (1.f + __expf(-5.f * (wdr[r] - rd)));
                    s = sv[tt][r] * 0.08838834765f - (1.f - sm) * 10000.f;
                }
                sv[tt][r] = s;
                mxr[r] = fmaxf(mxr[r], s);
            }
        } else {
#pragma unroll
            for (int r = 0; r < 4; ++r) sv[tt][r] = -3.0e38f;
        }
    }
#pragma unroll
    for (int r = 0; r < 4; ++r) {
        float m = mxr[r];
        m = fmaxf(m, __shfl_xor(m, 1));
        m = fmaxf(m, __shfl_xor(m, 2));
        m = fmaxf(m, __shfl_xor(m, 4));
        m = fmaxf(m, __shfl_xor(m, 8));
        mxr[r] = m;
    }
    if (l15 == 0) {
#pragma unroll
        for (int r = 0; r < 4; ++r) rmax[nfpar][qrb + r] = mxr[r];
    }
    __syncthreads();  // B2

    float mfin[4], smr[4];
#pragma unroll
    for (int r = 0; r < 4; ++r) {
        mfin[r] = fmaxf(rmax[0][qrb + r], rmax[1][qrb + r]);
        smr[r] = 0.f;
    }
#pragma unroll
    for (int tt = 0; tt < 7; ++tt) {
#pragma unroll
        for (int r = 0; r < 4; ++r) {
            const float e = __expf(sv[tt][r] - mfin[r]);
            sv[tt][r] = e;
            smr[r] += e;
        }
    }
#pragma unroll
    for (int r = 0; r < 4; ++r) {
        float s = smr[r];
        s += __shfl_xor(s, 1);
        s += __shfl_xor(s, 2);
        s += __shfl_xor(s, 4);
        s += __shfl_xor(s, 8);
        smr[r] = s;
    }
    if (l15 == 0) {
#pragma unroll
        for (int r = 0; r < 4; ++r) rsum[nfpar][qrb + r] = smr[r];
    }
    __syncthreads();  // B3

    float invr[4];
#pragma unroll
    for (int r = 0; r < 4; ++r) invr[r] = 1.f / (rsum[0][qrb + r] + rsum[1][qrb + r]);
#pragma unroll
    for (int tt = 0; tt < 7; ++tt) {
        const int nf = nfpar + 2 * tt;
        if (nf < 13) {
            const int n = nf * 16 + l15;
#pragma unroll
            for (int r = 0; r < 4; ++r)
                Pl[(qrb + r) * TSTRIDE + n] = f2bf(sv[tt][r] * invr[r]);
        }
    }
    __syncthreads();  // B4

    const int nh = wv & 1;
    f32x4 oacc[4];
#pragma unroll
    for (int nf2 = 0; nf2 < 4; ++nf2) oacc[nf2] = (f32x4){0.f, 0.f, 0.f, 0.f};
#pragma unroll
    for (int kf = 0; kf < 7; ++kf) {
        const bf16x8 pa = *(const bf16x8*)(Pl + (strip * 16 + l15) * TSTRIDE + kf * 32 + l4 * 8);
#pragma unroll
        for (int nf2 = 0; nf2 < 4; ++nf2) {
            const bf16x8 vf = *(const bf16x8*)(Vt + (nh * 64 + nf2 * 16 + l15) * TSTRIDE + kf * 32 + l4 * 8);
            oacc[nf2] = __builtin_amdgcn_mfma_f32_16x16x32_bf16(pa, vf, oacc[nf2], 0, 0, 0);
        }
    }
#pragma unroll
    for (int nf2 = 0; nf2 < 4; ++nf2) {
        const int cch = nh * 64 + nf2 * 16 + l15;
#pragma unroll
        for (int r = 0; r < 4; ++r) {
            const int qr = qrb + r;
            const int p = pbase + (i0 + (qr >> 3)) * 64 + j0 + (qr & 7);
            y[(size_t)p * C + cch] = f2bf(oacc[nf2][r] + bf2f(vb[(size_t)p * C + cch]));
        }
    }
}

// ---------------- Kernel 3: out = y @ W_out via MFMA (M=16384, N=128, K=128) ----------------
// Grid 256 (64-row tiles), 256 thr = 4 waves x 16-row strips.
__global__ __launch_bounds__(256) void out_kernel(const u16* __restrict__ yb,
                                                  const float* __restrict__ Wout,
                                                  float* __restrict__ out) {
    __shared__ u16 ys[64 * GST];
    __shared__ u16 wt[128 * GST];
    const int p0 = blockIdx.x * 64;
    const int tid = threadIdx.x;
    const int wv = tid >> 6;
    const int l = tid & 63;
    const int l15 = l & 15;
    const int l4 = l >> 4;

    // stage y (already bf16): 64 rows x 16 octets
    for (int f = tid; f < 1024; f += 256) {
        const int c8 = f & 15, r = f >> 4;
        *(uint4*)&ys[r * GST + c8 * 8] = *(const uint4*)(yb + (size_t)(p0 + r) * C + c8 * 8);
    }
    // stage W_out transposed (bf16)
    for (int f = tid; f < 4096; f += 256) {
        const int c = f & 127, kq = f >> 7;
        const float w0 = Wout[(size_t)(kq * 4 + 0) * C + c];
        const float w1 = Wout[(size_t)(kq * 4 + 1) * C + c];
        const float w2 = Wout[(size_t)(kq * 4 + 2) * C + c];
        const float w3 = Wout[(size_t)(kq * 4 + 3) * C + c];
        uint2 pk;
        pk.x = pack2(w0, w1);
        pk.y = pack2(w2, w3);
        *(uint2*)&wt[c * GST + kq * 4] = pk;
    }
    __syncthreads();

    const int strip = wv * 16;
    bf16x8 af[4];
#pragma unroll
    for (int kf = 0; kf < 4; ++kf)
        af[kf] = *(const bf16x8*)&ys[(strip + l15) * GST + kf * 32 + l4 * 8];

    f32x4 acc[8];
#pragma unroll
    for (int nf = 0; nf < 8; ++nf) acc[nf] = (f32x4){0.f, 0.f, 0.f, 0.f};
#pragma unroll
    for (int nf = 0; nf < 8; ++nf) {
#pragma unroll
        for (int kf = 0; kf < 4; ++kf) {
            const bf16x8 bf = *(const bf16x8*)&wt[(nf * 16 + l15) * GST + kf * 32 + l4 * 8];
            acc[nf] = __builtin_amdgcn_mfma_f32_16x16x32_bf16(af[kf], bf, acc[nf], 0, 0, 0);
        }
    }

#pragma unroll
    for (int nf = 0; nf < 8; ++nf) {
        const int col = nf * 16 + l15;
#pragma unroll
        for (int r = 0; r < 4; ++r) {
            const int row = strip + l4 * 4 + r;
            out[(size_t)(p0 + row) * C + col] = acc[nf][r];
        }
    }
}

extern "C" void kernel_launch(void* const* d_in, const int* in_sizes, int n_in,
                              void* d_out, int out_size, void* d_ws, size_t ws_size,
                              hipStream_t stream) {
    const float* x      = (const float*)d_in[0];
    const float* Wqkv   = (const float*)d_in[1];
    const float* Wwidth = (const float*)d_in[2];
    const float* bwidth = (const float*)d_in[3];
    const float* Wout   = (const float*)d_in[4];
    float* out = (float*)d_out;

    u16* qb = (u16*)d_ws;                           // 4 MB bf16
    u16* kb = qb + (size_t)NPIX * C;                // 4 MB bf16
    u16* vb = kb + (size_t)NPIX * C;                // 4 MB bf16
    float* width = (float*)(vb + (size_t)NPIX * C); // 64 KB fp32
    u16* yb = qb;   // alias: a block reads qb only for its own pixels before writing y there

    qkv_kernel<<<768, 256, 0, stream>>>(x, Wqkv, Wwidth, bwidth, qb, kb, vb, width);
    attn_kernel<<<256, 512, 0, stream>>>(qb, kb, vb, width, yb);
    out_kernel<<<NPIX / 64, 256, 0, stream>>>(yb, Wout, out);
}

// Round 8
// 39.350 us; speedup vs baseline: 4.5380x; 1.4067x over previous
//
#include <hip/hip_runtime.h>

#define C 128
#define NPIX 16384      // 4 * 64 * 64
#define THREE_C 384

typedef unsigned short u16;
typedef unsigned int u32;
typedef short bf16x8 __attribute__((ext_vector_type(8)));
typedef float f32x4 __attribute__((ext_vector_type(4)));

__device__ __forceinline__ float bf2f(u16 h) { return __uint_as_float(((u32)h) << 16); }
__device__ __forceinline__ u16 f2bf(float f) {
    u32 b = __float_as_uint(f);
    b += 0x7FFF + ((b >> 16) & 1);          // RNE
    return (u16)(b >> 16);
}
__device__ __forceinline__ u32 pack2(float a, float b) {
    return (u32)f2bf(a) | ((u32)f2bf(b) << 16);
}

// ---------------- Kernel 1: qkv = x @ W_qkv via MFMA (M=16384, N=384, K=128) ----------------
// 128-row tiles. Grid 384 = 128 row-tiles x 3 (nb: 0=q,1=k,2=v). 512 thr = 8 waves x 16-row strips.
#define GST 136

__global__ __launch_bounds__(512) void qkv_kernel(const float* __restrict__ x,
                                                  const float* __restrict__ Wqkv,
                                                  const float* __restrict__ Wwidth,
                                                  const float* __restrict__ bwidth,
                                                  u16* __restrict__ qb,
                                                  u16* __restrict__ kb,
                                                  u16* __restrict__ vb,
                                                  float* __restrict__ width_g) {
    __shared__ u16 xs[128 * GST];
    __shared__ u16 wt[128 * GST];
    const int rb = blockIdx.x / 3;
    const int nb = blockIdx.x % 3;
    const int p0 = rb * 128;
    const int tid = threadIdx.x;
    const int wv = tid >> 6;
    const int l = tid & 63;
    const int l15 = l & 15;
    const int l4 = l >> 4;

    // stage x rows (bf16): 128 rows x 32 k-quads
    for (int f = tid; f < 4096; f += 512) {
        const int kq = f & 31, r = f >> 5;
        const float4 xv = *(const float4*)(x + (size_t)(p0 + r) * C + kq * 4);
        uint2 pk;
        pk.x = pack2(xv.x, xv.y);
        pk.y = pack2(xv.z, xv.w);
        *(uint2*)&xs[r * GST + kq * 4] = pk;
    }
    // stage W transposed (bf16): 128 cols x 32 k-quads
    for (int f = tid; f < 4096; f += 512) {
        const int c = f & 127, kq = f >> 7;
        const float w0 = Wqkv[(size_t)(kq * 4 + 0) * THREE_C + nb * 128 + c];
        const float w1 = Wqkv[(size_t)(kq * 4 + 1) * THREE_C + nb * 128 + c];
        const float w2 = Wqkv[(size_t)(kq * 4 + 2) * THREE_C + nb * 128 + c];
        const float w3 = Wqkv[(size_t)(kq * 4 + 3) * THREE_C + nb * 128 + c];
        uint2 pk;
        pk.x = pack2(w0, w1);
        pk.y = pack2(w2, w3);
        *(uint2*)&wt[c * GST + kq * 4] = pk;
    }
    __syncthreads();

    if (nb == 0 && tid < 128) {
        float wacc = 0.f;
#pragma unroll
        for (int kk = 0; kk < C; ++kk) wacc += bf2f(xs[tid * GST + kk]) * Wwidth[kk];
        const float z = wacc + bwidth[0];
        width_g[p0 + tid] = (1.f / (1.f + __expf(-z))) * 4.242640687f + 0.5f;
    }

    const int strip = wv * 16;
    bf16x8 af[4];
#pragma unroll
    for (int kf = 0; kf < 4; ++kf)
        af[kf] = *(const bf16x8*)&xs[(strip + l15) * GST + kf * 32 + l4 * 8];

    f32x4 acc[8];
#pragma unroll
    for (int nf = 0; nf < 8; ++nf) acc[nf] = (f32x4){0.f, 0.f, 0.f, 0.f};
#pragma unroll
    for (int nf = 0; nf < 8; ++nf) {
#pragma unroll
        for (int kf = 0; kf < 4; ++kf) {
            const bf16x8 bf = *(const bf16x8*)&wt[(nf * 16 + l15) * GST + kf * 32 + l4 * 8];
            acc[nf] = __builtin_amdgcn_mfma_f32_16x16x32_bf16(af[kf], bf, acc[nf], 0, 0, 0);
        }
    }

    u16* dst = (nb == 0) ? qb : (nb == 1) ? kb : vb;
#pragma unroll
    for (int nf = 0; nf < 8; ++nf) {
        const int col = nf * 16 + l15;
#pragma unroll
        for (int r = 0; r < 4; ++r) {
            const int row = strip + l4 * 4 + r;
            dst[(size_t)(p0 + row) * C + col] = f2bf(acc[nf][r]);
        }
    }
}

// ---------------- Kernel 2: MFMA tile attention ----------------
// One block per 8x8 pixel tile (256 blocks, 1024 threads = 16 waves).
// Halo 14x14 = 196, N padded to 208 (13 frags), PV-K padded to 224.
// Staging writes zeros inline for OOB/pad (no separate memset pass).
#define HSTRIDE 136
#define TSTRIDE 232

__global__ __launch_bounds__(1024) void attn_kernel(const u16* __restrict__ qb,
                                                    const u16* __restrict__ kb,
                                                    const u16* __restrict__ vb,
                                                    const float* __restrict__ width_g,
                                                    u16* __restrict__ y) {
    __shared__ u16 Kl[208 * HSTRIDE];   // 56576 B
    __shared__ u16 Vt[128 * TSTRIDE];   // 59392 B
    __shared__ u16 Pl[64 * TSTRIDE];    // 29696 B
    __shared__ float rmax[4][64];
    __shared__ float rsum[4][64];
    __shared__ float wdl[64];

    const int tid = threadIdx.x;
    const int wv = tid >> 6;            // 0..15
    const int l = tid & 63;
    const int l15 = l & 15;
    const int l4 = l >> 4;

    const int W = ((int)blockIdx.x & 7) * 32 + ((int)blockIdx.x >> 3);  // XCD-chunked
    const int b = W >> 6;
    const int t = W & 63;
    const int i0 = (t >> 3) * 8;
    const int j0 = (t & 7) * 8;
    const int pbase = b * 4096;

    if (tid < 64)
        wdl[tid] = width_g[pbase + (i0 + (tid >> 3)) * 64 + j0 + (tid & 7)];

    // ---- K halo staging (zeros inline for OOB / pad rows 196-207) ----
    for (int f = tid; f < 3328; f += 1024) {          // 208 h x 16 c-octets
        const int c = f & 15, h = f >> 4;
        uint4 val = make_uint4(0, 0, 0, 0);
        if (h < 196) {
            const int hi = (h * 2341) >> 15;          // h / 14
            const int hj = h - hi * 14;
            const int ii = i0 - 3 + hi, jj = j0 - 3 + hj;
            if (((unsigned)ii < 64u) && ((unsigned)jj < 64u))
                val = *(const uint4*)(kb + (size_t)(pbase + ii * 64 + jj) * C + c * 8);
        }
        *(uint4*)&Kl[h * HSTRIDE + c * 8] = val;
    }
    // ---- V halo staging, transposed, pair-packed b32 writes (cols 0..223) ----
    for (int f = tid; f < 1792; f += 1024) {          // 112 h-pairs x 16 c-octets
        const int c8 = f & 15, h2 = f >> 4;
        const int h = h2 * 2;
        union { uint4 u4; u16 us[8]; } va, vz;
        va.u4 = make_uint4(0, 0, 0, 0);
        vz.u4 = make_uint4(0, 0, 0, 0);
        if (h < 196) {
            const int hi = (h * 2341) >> 15;
            const int hj = h - hi * 14;
            const int ii = i0 - 3 + hi, jj = j0 - 3 + hj;
            if (((unsigned)ii < 64u) && ((unsigned)jj < 64u))
                va.u4 = *(const uint4*)(vb + (size_t)(pbase + ii * 64 + jj) * C + c8 * 8);
        }
        if (h + 1 < 196) {
            const int hi = ((h + 1) * 2341) >> 15;
            const int hj = h + 1 - hi * 14;
            const int ii = i0 - 3 + hi, jj = j0 - 3 + hj;
            if (((unsigned)ii < 64u) && ((unsigned)jj < 64u))
                vz.u4 = *(const uint4*)(vb + (size_t)(pbase + ii * 64 + jj) * C + c8 * 8);
        }
#pragma unroll
        for (int s = 0; s < 8; ++s)
            *(u32*)&Vt[(c8 * 8 + s) * TSTRIDE + h] = (u32)va.us[s] | ((u32)vz.us[s] << 16);
    }

    // Q A-fragments direct from global
    const int strip = wv >> 2;                        // 0..3 (16 q rows each)
    const int g = wv & 3;                             // N-group / channel-quarter
    bf16x8 qf[4];
    {
        const int qr = strip * 16 + l15;
        const int p = pbase + (i0 + (qr >> 3)) * 64 + j0 + (qr & 7);
#pragma unroll
        for (int kf = 0; kf < 4; ++kf)
            qf[kf] = *(const bf16x8*)(qb + (size_t)p * C + kf * 32 + l4 * 8);
    }
    __syncthreads();  // B1: staging done

    // ---- QK^T: wave handles its strip x nf = g + 4*tt ----
    f32x4 sv[4];
#pragma unroll
    for (int tt = 0; tt < 4; ++tt) {
        const int nf = g + 4 * tt;
        f32x4 acc = {0.f, 0.f, 0.f, 0.f};
        if (nf < 13) {
            const u16* kr = Kl + (nf * 16 + l15) * HSTRIDE + l4 * 8;
#pragma unroll
            for (int kf = 0; kf < 4; ++kf)
                acc = __builtin_amdgcn_mfma_f32_16x16x32_bf16(
                    qf[kf], *(const bf16x8*)(kr + kf * 32), acc, 0, 0, 0);
        }
        sv[tt] = acc;
    }

    // ---- mask + penalty + group-local max ----
    const int qrb = strip * 16 + l4 * 4;
    float wdr[4], mxr[4];
#pragma unroll
    for (int r = 0; r < 4; ++r) { wdr[r] = wdl[qrb + r]; mxr[r] = -3.0e38f; }
#pragma unroll
    for (int tt = 0; tt < 4; ++tt) {
        const int nf = g + 4 * tt;
        if (nf < 13) {
            const int n = nf * 16 + l15;
            const int hi = (n * 2341) >> 15;
            const int hj = n - hi * 14;
#pragma unroll
            for (int r = 0; r < 4; ++r) {
                const int qr = qrb + r;
                const int di = hi - 3 - (qr >> 3);
                const int dj = hj - 3 - (qr & 7);
                const bool valid = ((unsigned)(di + 3) <= 6u) && ((unsigned)(dj + 3) <= 6u);
                float s = -3.0e38f;
                if (valid) {
                    const float rd = sqrtf((float)(di * di + dj * dj));
                    const float sm = 1.f / (1.f + __expf(-5.f * (wdr[r] - rd)));
                    s = sv[tt][r] * 0.08838834765f - (1.f - sm) * 10000.f;
                }
                sv[tt][r] = s;
                mxr[r] = fmaxf(mxr[r], s);
            }
        } else {
#pragma unroll
            for (int r = 0; r < 4; ++r) sv[tt][r] = -3.0e38f;
        }
    }
#pragma unroll
    for (int r = 0; r < 4; ++r) {
        float m = mxr[r];
        m = fmaxf(m, __shfl_xor(m, 1));
        m = fmaxf(m, __shfl_xor(m, 2));
        m = fmaxf(m, __shfl_xor(m, 4));
        m = fmaxf(m, __shfl_xor(m, 8));
        mxr[r] = m;                                   // group max m_g
    }
    // exp(s - m_g) and group-local sum
    float smr[4] = {0.f, 0.f, 0.f, 0.f};
#pragma unroll
    for (int tt = 0; tt < 4; ++tt) {
#pragma unroll
        for (int r = 0; r < 4; ++r) {
            const float e = __expf(sv[tt][r] - mxr[r]);
            sv[tt][r] = e;
            smr[r] += e;
        }
    }
#pragma unroll
    for (int r = 0; r < 4; ++r) {
        float s = smr[r];
        s += __shfl_xor(s, 1);
        s += __shfl_xor(s, 2);
        s += __shfl_xor(s, 4);
        s += __shfl_xor(s, 8);
        smr[r] = s;
    }
    if (l15 == 0) {
#pragma unroll
        for (int r = 0; r < 4; ++r) {
            rmax[g][qrb + r] = mxr[r];
            rsum[g][qrb + r] = smr[r];
        }
    }
    __syncthreads();  // B2: stats

    // combine: m = max_g m_g; total = sum_g s_g * exp(m_g - m); fac = exp(m_g - m)/total
    float fac[4];
#pragma unroll
    for (int r = 0; r < 4; ++r) {
        const int qr = qrb + r;
        const float m0 = rmax[0][qr], m1 = rmax[1][qr], m2 = rmax[2][qr], m3 = rmax[3][qr];
        const float mf = fmaxf(fmaxf(m0, m1), fmaxf(m2, m3));
        const float tot = rsum[0][qr] * __expf(m0 - mf) + rsum[1][qr] * __expf(m1 - mf)
                        + rsum[2][qr] * __expf(m2 - mf) + rsum[3][qr] * __expf(m3 - mf);
        fac[r] = __expf(mxr[r] - mf) / tot;
    }
#pragma unroll
    for (int tt = 0; tt < 4; ++tt) {
        const int nf = g + 4 * tt;
        if (nf < 13) {
            const int n = nf * 16 + l15;
#pragma unroll
            for (int r = 0; r < 4; ++r)
                Pl[(qrb + r) * TSTRIDE + n] = f2bf(sv[tt][r] * fac[r]);
        } else if (nf == 13) {                        // zero pad cols 208-223
            const int n = 208 + l15;
#pragma unroll
            for (int r = 0; r < 4; ++r)
                Pl[(qrb + r) * TSTRIDE + n] = 0;
        }
    }
    __syncthreads();  // B3: P ready

    // ---- PV: O = P @ V, K = 224 (7 frags); wave: strip x channel-quarter g ----
    f32x4 oacc[2];
    oacc[0] = (f32x4){0.f, 0.f, 0.f, 0.f};
    oacc[1] = (f32x4){0.f, 0.f, 0.f, 0.f};
#pragma unroll
    for (int kf = 0; kf < 7; ++kf) {
        const bf16x8 pa = *(const bf16x8*)(Pl + (strip * 16 + l15) * TSTRIDE + kf * 32 + l4 * 8);
#pragma unroll
        for (int nf2 = 0; nf2 < 2; ++nf2) {
            const bf16x8 vf = *(const bf16x8*)(Vt + (g * 32 + nf2 * 16 + l15) * TSTRIDE + kf * 32 + l4 * 8);
            oacc[nf2] = __builtin_amdgcn_mfma_f32_16x16x32_bf16(pa, vf, oacc[nf2], 0, 0, 0);
        }
    }
#pragma unroll
    for (int nf2 = 0; nf2 < 2; ++nf2) {
        const int cch = g * 32 + nf2 * 16 + l15;
#pragma unroll
        for (int r = 0; r < 4; ++r) {
            const int qr = qrb + r;
            const int p = pbase + (i0 + (qr >> 3)) * 64 + j0 + (qr & 7);
            y[(size_t)p * C + cch] = f2bf(oacc[nf2][r] + bf2f(vb[(size_t)p * C + cch]));
        }
    }
}

// ---------------- Kernel 3: out = y @ W_out via MFMA (M=16384, N=128, K=128) ----------------
// 128-row tiles, grid 128, 512 thr = 8 waves x 16-row strips.
__global__ __launch_bounds__(512) void out_kernel(const u16* __restrict__ yb,
                                                  const float* __restrict__ Wout,
                                                  float* __restrict__ out) {
    __shared__ u16 ys[128 * GST];
    __shared__ u16 wt[128 * GST];
    const int p0 = blockIdx.x * 128;
    const int tid = threadIdx.x;
    const int wv = tid >> 6;
    const int l = tid & 63;
    const int l15 = l & 15;
    const int l4 = l >> 4;

    for (int f = tid; f < 2048; f += 512) {           // y already bf16
        const int c8 = f & 15, r = f >> 4;
        *(uint4*)&ys[r * GST + c8 * 8] = *(const uint4*)(yb + (size_t)(p0 + r) * C + c8 * 8);
    }
    for (int f = tid; f < 4096; f += 512) {
        const int c = f & 127, kq = f >> 7;
        const float w0 = Wout[(size_t)(kq * 4 + 0) * C + c];
        const float w1 = Wout[(size_t)(kq * 4 + 1) * C + c];
        const float w2 = Wout[(size_t)(kq * 4 + 2) * C + c];
        const float w3 = Wout[(size_t)(kq * 4 + 3) * C + c];
        uint2 pk;
        pk.x = pack2(w0, w1);
        pk.y = pack2(w2, w3);
        *(uint2*)&wt[c * GST + kq * 4] = pk;
    }
    __syncthreads();

    const int strip = wv * 16;
    bf16x8 af[4];
#pragma unroll
    for (int kf = 0; kf < 4; ++kf)
        af[kf] = *(const bf16x8*)&ys[(strip + l15) * GST + kf * 32 + l4 * 8];

    f32x4 acc[8];
#pragma unroll
    for (int nf = 0; nf < 8; ++nf) acc[nf] = (f32x4){0.f, 0.f, 0.f, 0.f};
#pragma unroll
    for (int nf = 0; nf < 8; ++nf) {
#pragma unroll
        for (int kf = 0; kf < 4; ++kf) {
            const bf16x8 bf = *(const bf16x8*)&wt[(nf * 16 + l15) * GST + kf * 32 + l4 * 8];
            acc[nf] = __builtin_amdgcn_mfma_f32_16x16x32_bf16(af[kf], bf, acc[nf], 0, 0, 0);
        }
    }

#pragma unroll
    for (int nf = 0; nf < 8; ++nf) {
        const int col = nf * 16 + l15;
#pragma unroll
        for (int r = 0; r < 4; ++r) {
            const int row = strip + l4 * 4 + r;
            out[(size_t)(p0 + row) * C + col] = acc[nf][r];
        }
    }
}

extern "C" void kernel_launch(void* const* d_in, const int* in_sizes, int n_in,
                              void* d_out, int out_size, void* d_ws, size_t ws_size,
                              hipStream_t stream) {
    const float* x      = (const float*)d_in[0];
    const float* Wqkv   = (const float*)d_in[1];
    const float* Wwidth = (const float*)d_in[2];
    const float* bwidth = (const float*)d_in[3];
    const float* Wout   = (const float*)d_in[4];
    float* out = (float*)d_out;

    u16* qb = (u16*)d_ws;                           // 4 MB bf16
    u16* kb = qb + (size_t)NPIX * C;                // 4 MB bf16
    u16* vb = kb + (size_t)NPIX * C;                // 4 MB bf16
    float* width = (float*)(vb + (size_t)NPIX * C); // 64 KB fp32
    u16* yb = qb;   // alias: a block reads qb only for its own pixels before writing y there

    qkv_kernel<<<384, 512, 0, stream>>>(x, Wqkv, Wwidth, bwidth, qb, kb, vb, width);
    attn_kernel<<<256, 1024, 0, stream>>>(qb, kb, vb, width, yb);
    out_kernel<<<128, 512, 0, stream>>>(yb, Wout, out);
}

// Round 9
// 30.702 us; speedup vs baseline: 5.8163x; 1.2817x over previous
//
#include <hip/hip_runtime.h>

#define C 128
#define NPIX 16384      // 4 * 64 * 64
#define THREE_C 384

typedef unsigned short u16;
typedef unsigned int u32;
typedef short bf16x8 __attribute__((ext_vector_type(8)));
typedef float f32x4 __attribute__((ext_vector_type(4)));

__device__ __forceinline__ float bf2f(u16 h) { return __uint_as_float(((u32)h) << 16); }
__device__ __forceinline__ u16 f2bf(float f) {
    u32 b = __float_as_uint(f);
    b += 0x7FFF + ((b >> 16) & 1);          // RNE
    return (u16)(b >> 16);
}
__device__ __forceinline__ u32 pack2(float a, float b) {
    return (u32)f2bf(a) | ((u32)f2bf(b) << 16);
}

// ---------------- Kernel 1: qkv = x @ W_qkv via MFMA (M=16384, N=384, K=128) ----------------
// 128-row tiles. Grid 384; XCD-grouped so the 3 nb-blocks of a row-tile share one XCD's L2.
// 512 thr = 8 waves x 16-row strips.
#define GST 136

__global__ __launch_bounds__(512) void qkv_kernel(const float* __restrict__ x,
                                                  const float* __restrict__ Wqkv,
                                                  const float* __restrict__ Wwidth,
                                                  const float* __restrict__ bwidth,
                                                  u16* __restrict__ qb,
                                                  u16* __restrict__ kb,
                                                  u16* __restrict__ vb,
                                                  float* __restrict__ width_g) {
    __shared__ u16 xs[128 * GST];
    __shared__ u16 wt[128 * GST];
    // XCD grouping: XCD x gets tasks [48x, 48x+48) = row-tiles [16x,16x+16) x all 3 nb
    const int task = ((int)(blockIdx.x & 7)) * 48 + ((int)blockIdx.x >> 3);
    const int rb = task / 3;
    const int nb = task % 3;
    const int p0 = rb * 128;
    const int tid = threadIdx.x;
    const int wv = tid >> 6;
    const int l = tid & 63;
    const int l15 = l & 15;
    const int l4 = l >> 4;

    // stage x rows (bf16): 128 rows x 32 k-quads
    for (int f = tid; f < 4096; f += 512) {
        const int kq = f & 31, r = f >> 5;
        const float4 xv = *(const float4*)(x + (size_t)(p0 + r) * C + kq * 4);
        uint2 pk;
        pk.x = pack2(xv.x, xv.y);
        pk.y = pack2(xv.z, xv.w);
        *(uint2*)&xs[r * GST + kq * 4] = pk;
    }
    // stage W transposed (bf16): 128 cols x 32 k-quads
    for (int f = tid; f < 4096; f += 512) {
        const int c = f & 127, kq = f >> 7;
        const float w0 = Wqkv[(size_t)(kq * 4 + 0) * THREE_C + nb * 128 + c];
        const float w1 = Wqkv[(size_t)(kq * 4 + 1) * THREE_C + nb * 128 + c];
        const float w2 = Wqkv[(size_t)(kq * 4 + 2) * THREE_C + nb * 128 + c];
        const float w3 = Wqkv[(size_t)(kq * 4 + 3) * THREE_C + nb * 128 + c];
        uint2 pk;
        pk.x = pack2(w0, w1);
        pk.y = pack2(w2, w3);
        *(uint2*)&wt[c * GST + kq * 4] = pk;
    }
    __syncthreads();

    if (nb == 0 && tid < 128) {
        float wacc = 0.f;
#pragma unroll
        for (int kk = 0; kk < C; ++kk) wacc += bf2f(xs[tid * GST + kk]) * Wwidth[kk];
        const float z = wacc + bwidth[0];
        width_g[p0 + tid] = (1.f / (1.f + __expf(-z))) * 4.242640687f + 0.5f;
    }

    const int strip = wv * 16;
    bf16x8 af[4];
#pragma unroll
    for (int kf = 0; kf < 4; ++kf)
        af[kf] = *(const bf16x8*)&xs[(strip + l15) * GST + kf * 32 + l4 * 8];

    f32x4 acc[8];
#pragma unroll
    for (int nf = 0; nf < 8; ++nf) acc[nf] = (f32x4){0.f, 0.f, 0.f, 0.f};
#pragma unroll
    for (int nf = 0; nf < 8; ++nf) {
#pragma unroll
        for (int kf = 0; kf < 4; ++kf) {
            const bf16x8 bf = *(const bf16x8*)&wt[(nf * 16 + l15) * GST + kf * 32 + l4 * 8];
            acc[nf] = __builtin_amdgcn_mfma_f32_16x16x32_bf16(af[kf], bf, acc[nf], 0, 0, 0);
        }
    }

    u16* dst = (nb == 0) ? qb : (nb == 1) ? kb : vb;
#pragma unroll
    for (int nf = 0; nf < 8; ++nf) {
        const int col = nf * 16 + l15;
#pragma unroll
        for (int r = 0; r < 4; ++r) {
            const int row = strip + l4 * 4 + r;
            dst[(size_t)(p0 + row) * C + col] = f2bf(acc[nf][r]);
        }
    }
}

// ---------------- Kernel 2: fused MFMA tile attention + output projection ----------------
// One block per 8x8 pixel tile (256 blocks, 1024 threads = 16 waves).
// Halo 14x14 = 196, N padded to 208 (13 frags), PV-K padded to 224.
// After QK^T, Kl's LDS is reused for W_out^T; after PV, Pl's LDS is reused for y;
// the final phase computes out = y @ W_out and writes d_out directly.
#define HSTRIDE 136
#define TSTRIDE 232

__global__ __launch_bounds__(1024) void attn_kernel(const u16* __restrict__ qb,
                                                    const u16* __restrict__ kb,
                                                    const u16* __restrict__ vb,
                                                    const float* __restrict__ width_g,
                                                    const float* __restrict__ Wout,
                                                    float* __restrict__ out) {
    __shared__ u16 Kl[208 * HSTRIDE];   // 56576 B (also holds W_out^T bf16 later: 128*GST)
    __shared__ u16 Vt[128 * TSTRIDE];   // 59392 B
    __shared__ u16 Pl[64 * TSTRIDE];    // 29696 B (also holds y bf16 later: 64*GST)
    __shared__ float rmax[4][64];
    __shared__ float rsum[4][64];
    __shared__ float wdl[64];

    const int tid = threadIdx.x;
    const int wv = tid >> 6;            // 0..15
    const int l = tid & 63;
    const int l15 = l & 15;
    const int l4 = l >> 4;

    const int W = ((int)blockIdx.x & 7) * 32 + ((int)blockIdx.x >> 3);  // XCD-chunked
    const int b = W >> 6;
    const int t = W & 63;
    const int i0 = (t >> 3) * 8;
    const int j0 = (t & 7) * 8;
    const int pbase = b * 4096;

    if (tid < 64)
        wdl[tid] = width_g[pbase + (i0 + (tid >> 3)) * 64 + j0 + (tid & 7)];

    // ---- K halo staging (zeros inline for OOB / pad rows 196-207) ----
    for (int f = tid; f < 3328; f += 1024) {          // 208 h x 16 c-octets
        const int c = f & 15, h = f >> 4;
        uint4 val = make_uint4(0, 0, 0, 0);
        if (h < 196) {
            const int hi = (h * 2341) >> 15;          // h / 14
            const int hj = h - hi * 14;
            const int ii = i0 - 3 + hi, jj = j0 - 3 + hj;
            if (((unsigned)ii < 64u) && ((unsigned)jj < 64u))
                val = *(const uint4*)(kb + (size_t)(pbase + ii * 64 + jj) * C + c * 8);
        }
        *(uint4*)&Kl[h * HSTRIDE + c * 8] = val;
    }
    // ---- V halo staging, transposed, pair-packed b32 writes (cols 0..223) ----
    for (int f = tid; f < 1792; f += 1024) {          // 112 h-pairs x 16 c-octets
        const int c8 = f & 15, h2 = f >> 4;
        const int h = h2 * 2;
        union { uint4 u4; u16 us[8]; } va, vz;
        va.u4 = make_uint4(0, 0, 0, 0);
        vz.u4 = make_uint4(0, 0, 0, 0);
        if (h < 196) {
            const int hi = (h * 2341) >> 15;
            const int hj = h - hi * 14;
            const int ii = i0 - 3 + hi, jj = j0 - 3 + hj;
            if (((unsigned)ii < 64u) && ((unsigned)jj < 64u))
                va.u4 = *(const uint4*)(vb + (size_t)(pbase + ii * 64 + jj) * C + c8 * 8);
        }
        if (h + 1 < 196) {
            const int hi = ((h + 1) * 2341) >> 15;
            const int hj = h + 1 - hi * 14;
            const int ii = i0 - 3 + hi, jj = j0 - 3 + hj;
            if (((unsigned)ii < 64u) && ((unsigned)jj < 64u))
                vz.u4 = *(const uint4*)(vb + (size_t)(pbase + ii * 64 + jj) * C + c8 * 8);
        }
#pragma unroll
        for (int s = 0; s < 8; ++s)
            *(u32*)&Vt[(c8 * 8 + s) * TSTRIDE + h] = (u32)va.us[s] | ((u32)vz.us[s] << 16);
    }

    // Q A-fragments direct from global
    const int strip = wv >> 2;                        // 0..3 (16 q rows each)
    const int g = wv & 3;                             // N-group / channel-quarter
    bf16x8 qf[4];
    {
        const int qr = strip * 16 + l15;
        const int p = pbase + (i0 + (qr >> 3)) * 64 + j0 + (qr & 7);
#pragma unroll
        for (int kf = 0; kf < 4; ++kf)
            qf[kf] = *(const bf16x8*)(qb + (size_t)p * C + kf * 32 + l4 * 8);
    }
    __syncthreads();  // B1: staging done

    // ---- QK^T: wave handles its strip x nf = g + 4*tt ----
    f32x4 sv[4];
#pragma unroll
    for (int tt = 0; tt < 4; ++tt) {
        const int nf = g + 4 * tt;
        f32x4 acc = {0.f, 0.f, 0.f, 0.f};
        if (nf < 13) {
            const u16* kr = Kl + (nf * 16 + l15) * HSTRIDE + l4 * 8;
#pragma unroll
            for (int kf = 0; kf < 4; ++kf)
                acc = __builtin_amdgcn_mfma_f32_16x16x32_bf16(
                    qf[kf], *(const bf16x8*)(kr + kf * 32), acc, 0, 0, 0);
        }
        sv[tt] = acc;
    }

    // ---- mask + penalty + group-local max ----
    const int qrb = strip * 16 + l4 * 4;
    float wdr[4], mxr[4];
#pragma unroll
    for (int r = 0; r < 4; ++r) { wdr[r] = wdl[qrb + r]; mxr[r] = -3.0e38f; }
#pragma unroll
    for (int tt = 0; tt < 4; ++tt) {
        const int nf = g + 4 * tt;
        if (nf < 13) {
            const int n = nf * 16 + l15;
            const int hi = (n * 2341) >> 15;
            const int hj = n - hi * 14;
#pragma unroll
            for (int r = 0; r < 4; ++r) {
                const int qr = qrb + r;
                const int di = hi - 3 - (qr >> 3);
                const int dj = hj - 3 - (qr & 7);
                const bool valid = ((unsigned)(di + 3) <= 6u) && ((unsigned)(dj + 3) <= 6u);
                float s = -3.0e38f;
                if (valid) {
                    const float rd = sqrtf((float)(di * di + dj * dj));
                    const float sm = 1.f / (1.f + __expf(-5.f * (wdr[r] - rd)));
                    s = sv[tt][r] * 0.08838834765f - (1.f - sm) * 10000.f;
                }
                sv[tt][r] = s;
                mxr[r] = fmaxf(mxr[r], s);
            }
        } else {
#pragma unroll
            for (int r = 0; r < 4; ++r) sv[tt][r] = -3.0e38f;
        }
    }
#pragma unroll
    for (int r = 0; r < 4; ++r) {
        float m = mxr[r];
        m = fmaxf(m, __shfl_xor(m, 1));
        m = fmaxf(m, __shfl_xor(m, 2));
        m = fmaxf(m, __shfl_xor(m, 4));
        m = fmaxf(m, __shfl_xor(m, 8));
        mxr[r] = m;                                   // group max m_g
    }
    float smr[4] = {0.f, 0.f, 0.f, 0.f};
#pragma unroll
    for (int tt = 0; tt < 4; ++tt) {
#pragma unroll
        for (int r = 0; r < 4; ++r) {
            const float e = __expf(sv[tt][r] - mxr[r]);
            sv[tt][r] = e;
            smr[r] += e;
        }
    }
#pragma unroll
    for (int r = 0; r < 4; ++r) {
        float s = smr[r];
        s += __shfl_xor(s, 1);
        s += __shfl_xor(s, 2);
        s += __shfl_xor(s, 4);
        s += __shfl_xor(s, 8);
        smr[r] = s;
    }
    if (l15 == 0) {
#pragma unroll
        for (int r = 0; r < 4; ++r) {
            rmax[g][qrb + r] = mxr[r];
            rsum[g][qrb + r] = smr[r];
        }
    }
    __syncthreads();  // B2: stats ready; Kl (K halo) now dead

    // ---- stage W_out^T bf16 into Kl region (for the fused output projection) ----
    u16* wtl = Kl;
    for (int f = tid; f < 4096; f += 1024) {
        const int c = f & 127, kq = f >> 7;
        const float w0 = Wout[(size_t)(kq * 4 + 0) * C + c];
        const float w1 = Wout[(size_t)(kq * 4 + 1) * C + c];
        const float w2 = Wout[(size_t)(kq * 4 + 2) * C + c];
        const float w3 = Wout[(size_t)(kq * 4 + 3) * C + c];
        uint2 pk;
        pk.x = pack2(w0, w1);
        pk.y = pack2(w2, w3);
        *(uint2*)&wtl[c * GST + kq * 4] = pk;
    }

    // combine softmax stats; write normalized P (bf16)
    float fac[4];
#pragma unroll
    for (int r = 0; r < 4; ++r) {
        const int qr = qrb + r;
        const float m0 = rmax[0][qr], m1 = rmax[1][qr], m2 = rmax[2][qr], m3 = rmax[3][qr];
        const float mf = fmaxf(fmaxf(m0, m1), fmaxf(m2, m3));
        const float tot = rsum[0][qr] * __expf(m0 - mf) + rsum[1][qr] * __expf(m1 - mf)
                        + rsum[2][qr] * __expf(m2 - mf) + rsum[3][qr] * __expf(m3 - mf);
        fac[r] = __expf(mxr[r] - mf) / tot;
    }
#pragma unroll
    for (int tt = 0; tt < 4; ++tt) {
        const int nf = g + 4 * tt;
        if (nf < 13) {
            const int n = nf * 16 + l15;
#pragma unroll
            for (int r = 0; r < 4; ++r)
                Pl[(qrb + r) * TSTRIDE + n] = f2bf(sv[tt][r] * fac[r]);
        } else if (nf == 13) {                        // zero pad cols 208-223
            const int n = 208 + l15;
#pragma unroll
            for (int r = 0; r < 4; ++r)
                Pl[(qrb + r) * TSTRIDE + n] = 0;
        }
    }
    __syncthreads();  // B3: P + W_out^T ready

    // ---- PV: O = P @ V, K = 224 (7 frags); wave: strip x channel-quarter g ----
    f32x4 oacc[2];
    oacc[0] = (f32x4){0.f, 0.f, 0.f, 0.f};
    oacc[1] = (f32x4){0.f, 0.f, 0.f, 0.f};
#pragma unroll
    for (int kf = 0; kf < 7; ++kf) {
        const bf16x8 pa = *(const bf16x8*)(Pl + (strip * 16 + l15) * TSTRIDE + kf * 32 + l4 * 8);
#pragma unroll
        for (int nf2 = 0; nf2 < 2; ++nf2) {
            const bf16x8 vf = *(const bf16x8*)(Vt + (g * 32 + nf2 * 16 + l15) * TSTRIDE + kf * 32 + l4 * 8);
            oacc[nf2] = __builtin_amdgcn_mfma_f32_16x16x32_bf16(pa, vf, oacc[nf2], 0, 0, 0);
        }
    }
    __syncthreads();  // B4: PV done; Pl region dead

    // ---- y = O + v (bf16) into Pl region (stride GST); v read from Vt ----
    u16* ylds = Pl;
#pragma unroll
    for (int nf2 = 0; nf2 < 2; ++nf2) {
        const int cch = g * 32 + nf2 * 16 + l15;
#pragma unroll
        for (int r = 0; r < 4; ++r) {
            const int qr = qrb + r;
            const int h = 45 + (qr >> 3) * 14 + (qr & 7);   // own pixel's halo index
            const float vv = bf2f(Vt[cch * TSTRIDE + h]);
            ylds[qr * GST + cch] = f2bf(oacc[nf2][r] + vv);
        }
    }
    __syncthreads();  // B5: y ready

    // ---- fused output projection: out = y @ W_out ----
    bf16x8 yf[4];
#pragma unroll
    for (int kf = 0; kf < 4; ++kf)
        yf[kf] = *(const bf16x8*)&ylds[(strip * 16 + l15) * GST + kf * 32 + l4 * 8];

    f32x4 oc[2];
    oc[0] = (f32x4){0.f, 0.f, 0.f, 0.f};
    oc[1] = (f32x4){0.f, 0.f, 0.f, 0.f};
#pragma unroll
    for (int u = 0; u < 2; ++u) {
        const int nf = g + 4 * u;
#pragma unroll
        for (int kf = 0; kf < 4; ++kf) {
            const bf16x8 bf = *(const bf16x8*)&wtl[(nf * 16 + l15) * GST + kf * 32 + l4 * 8];
            oc[u] = __builtin_amdgcn_mfma_f32_16x16x32_bf16(yf[kf], bf, oc[u], 0, 0, 0);
        }
    }
#pragma unroll
    for (int u = 0; u < 2; ++u) {
        const int col = (g + 4 * u) * 16 + l15;
#pragma unroll
        for (int r = 0; r < 4; ++r) {
            const int qr = qrb + r;
            const int p = pbase + (i0 + (qr >> 3)) * 64 + j0 + (qr & 7);
            out[(size_t)p * C + col] = oc[u][r];
        }
    }
}

extern "C" void kernel_launch(void* const* d_in, const int* in_sizes, int n_in,
                              void* d_out, int out_size, void* d_ws, size_t ws_size,
                              hipStream_t stream) {
    const float* x      = (const float*)d_in[0];
    const float* Wqkv   = (const float*)d_in[1];
    const float* Wwidth = (const float*)d_in[2];
    const float* bwidth = (const float*)d_in[3];
    const float* Wout   = (const float*)d_in[4];
    float* out = (float*)d_out;

    u16* qb = (u16*)d_ws;                           // 4 MB bf16
    u16* kb = qb + (size_t)NPIX * C;                // 4 MB bf16
    u16* vb = kb + (size_t)NPIX * C;                // 4 MB bf16
    float* width = (float*)(vb + (size_t)NPIX * C); // 64 KB fp32

    qkv_kernel<<<384, 512, 0, stream>>>(x, Wqkv, Wwidth, bwidth, qb, kb, vb, width);
    attn_kernel<<<256, 1024, 0, stream>>>(qb, kb, vb, width, Wout, out);
}